// Round 13
// baseline (334.182 us; speedup 1.0000x reference)
//
#include <hip/hip_runtime.h>
#include <stdint.h>

namespace {

typedef __attribute__((ext_vector_type(8)))  short short8;   // 8 bf16
typedef __attribute__((ext_vector_type(16))) float f32x16;
typedef __attribute__((ext_vector_type(4)))  float f32x4;

union U4 {
    uint4    q;
    uint32_t u[4];
    uint16_t us[8];
    short8   s8;
};

constexpr float INV_SCALE = 0.08838834764831845f;  // 1/sqrt(128), BOTH attn blocks

// ---- workspace (weight fragment) layout, bytes (prepack UNCHANGED) ----
constexpr size_t WSPROJ = 65536;            // 4c*8kb*2(hi,lo)*1024
constexpr size_t WP1OFF = 6 * WSPROJ;       // Wp1: c=0..7, kb=0..7 -> 131072 B
constexpr size_t WP2OFF = WP1OFF + 131072;  // Wp2 (16x16 frags): kb=0..7 -> 16384 B

// ---- LDS arena: 65536 B, TWO batches row-stacked (64 rows), 2 blocks/CU ----
constexpr int AH_OFF = 0;       // X/WAV/NF hi plane bf16 [64][128], swizzled, 16KB
constexpr int AL_OFF = 16384;   // X/WAV/NF lo plane 16KB; Q plane ALIASES (X-lo dead post-proj)
constexpr int KB_OFF = 32768;   // K plane bf16 [64][128] 16KB; S fp32 [64][36dw] aliases post-S-read
constexpr int VT_OFF = 49152;   // V 1-term RNE plane [128 e][64 m] bf16, swizzled, 16KB
// H bf16 [64][256] (32KB) aliases KB+VT at MLP time; policy logits alias AH.

__device__ __forceinline__ int pl_addr(int base, int n, int e) {   // bf16 plane [64][128]
    return base + ((n * 256 + e * 2) ^ ((n & 15) << 4));
}
__device__ __forceinline__ int vt_addr(int e, int m) {             // bf16 [128][64]
    return VT_OFF + ((e * 128 + m * 2) ^ ((e & 7) << 4));
}
__device__ __forceinline__ int s_addr(int n, int m) {              // fp32 [64][36dw], over KB
    return KB_OFF + n * 144 + m * 4;
}
__device__ __forceinline__ int h_addr(int n, int h) {              // bf16 [64][256], over KB+VT
    return KB_OFF + ((n * 512 + h * 2) ^ ((n & 15) << 4));
}
__device__ __forceinline__ int ps_addr(int n, int a) {             // fp32 [64][36dw], over AH
    return AH_OFF + n * 144 + a * 4;
}

__device__ __forceinline__ uint16_t f2bf_rne(float x) {
    uint32_t u = __float_as_uint(x);
    u += 0x7FFFu + ((u >> 16) & 1u);
    return (uint16_t)(u >> 16);
}

// split 8 fp32 -> (hi bf16x8, lo bf16x8); hi = trunc, lo = trunc(x - hi)
__device__ __forceinline__ void split8(float4 a, float4 b, short8& hi, short8& lo) {
    float xs[8] = {a.x, a.y, a.z, a.w, b.x, b.y, b.z, b.w};
    U4 h, l;
#pragma unroll
    for (int p = 0; p < 4; ++p) {
        uint32_t b0 = __float_as_uint(xs[2 * p]);
        uint32_t b1 = __float_as_uint(xs[2 * p + 1]);
        float r0 = xs[2 * p]     - __uint_as_float(b0 & 0xFFFF0000u);
        float r1 = xs[2 * p + 1] - __uint_as_float(b1 & 0xFFFF0000u);
        h.u[p] = __builtin_amdgcn_perm(b1, b0, 0x07060302u);
        l.u[p] = __builtin_amdgcn_perm(__float_as_uint(r1), __float_as_uint(r0), 0x07060302u);
    }
    hi = h.s8; lo = l.s8;
}

// fill per-wave A-fragment register cache from ACT planes (16 ds_read_b128, ONCE)
__device__ __forceinline__ void fill_a(const char* smem, int rowoff, int l,
                                       U4* ahr, U4* alr) {
    const int n = rowoff + (l & 31), half = l >> 5;
#pragma unroll
    for (int kb = 0; kb < 8; ++kb) {
        const int d0 = kb * 16 + half * 8;
        ahr[kb].q = *(const uint4*)(smem + pl_addr(AH_OFF, n, d0));
        alr[kb].q = *(const uint4*)(smem + pl_addr(AL_OFF, n, d0));
    }
}

// 32-row GEMM tile with REGISTER-CACHED A (zero LDS reads): B loads + 24 MFMA.
__device__ __forceinline__ f32x16 gemm32c(const U4* ahr, const U4* alr,
                                          const uint8_t* __restrict__ matbase,
                                          int c, int l) {
    f32x16 acc = {0.f,0.f,0.f,0.f, 0.f,0.f,0.f,0.f, 0.f,0.f,0.f,0.f, 0.f,0.f,0.f,0.f};
#pragma unroll
    for (int kb = 0; kb < 8; ++kb) {
        const uint8_t* p = matbase + (size_t)((c * 8 + kb) * 2) * 1024 + (size_t)l * 16;
        U4 bh, bl;
        bh.q = *(const uint4*)p;
        bl.q = *(const uint4*)(p + 1024);
        acc = __builtin_amdgcn_mfma_f32_32x32x16_bf16(ahr[kb].s8, bh.s8, acc, 0, 0, 0);
        acc = __builtin_amdgcn_mfma_f32_32x32x16_bf16(alr[kb].s8, bh.s8, acc, 0, 0, 0);
        acc = __builtin_amdgcn_mfma_f32_32x32x16_bf16(ahr[kb].s8, bl.s8, acc, 0, 0, 0);
    }
    return acc;
}

// store 32x32 D-tile as 1-term RNE bf16 plane at row offset
__device__ __forceinline__ void store_plane32(char* smem, int base, int rowoff, int c, int l,
                                              const f32x16& a) {
    const int e = c * 32 + (l & 31);
    const int half = l >> 5;
#pragma unroll
    for (int r = 0; r < 16; ++r) {
        int n = rowoff + (r & 3) + 8 * (r >> 2) + 4 * half;   // verified 32x32 D mapping
        *(uint16_t*)(smem + pl_addr(base, n, e)) = f2bf_rne(a[r]);
    }
}

// store 32x32 D-tile as hi/lo trunc-split ACT planes at row offset
__device__ __forceinline__ void store_act32(char* smem, int rowoff, int c, int l, const f32x16& a) {
    const int e = c * 32 + (l & 31);
    const int half = l >> 5;
#pragma unroll
    for (int r = 0; r < 16; ++r) {
        int n = rowoff + (r & 3) + 8 * (r >> 2) + 4 * half;
        uint32_t bu = __float_as_uint(a[r]);
        float rr = a[r] - __uint_as_float(bu & 0xFFFF0000u);
        *(uint16_t*)(smem + pl_addr(AH_OFF, n, e)) = (uint16_t)(bu >> 16);
        *(uint16_t*)(smem + pl_addr(AL_OFF, n, e)) = (uint16_t)(__float_as_uint(rr) >> 16);
    }
}

// -------- pre-pass: convert weights to fragment-ordered split-bf16 in d_ws --------
__global__ void prepack(const float* __restrict__ Wk1, const float* __restrict__ Wq1,
                        const float* __restrict__ Wv1, const float* __restrict__ Wk2,
                        const float* __restrict__ Wq2, const float* __restrict__ Wv2,
                        const float* __restrict__ Wp1, const float* __restrict__ Wp2,
                        uint8_t* __restrict__ wsb) {
    const int bid = blockIdx.x;
    const int l = threadIdx.x;
    float4 fa = make_float4(0.f, 0.f, 0.f, 0.f), fb = fa;
    uint8_t* dst;
    if (bid < 192) {                       // 6 proj matrices, 32x32 B-frags
        int m = bid >> 5, rem = bid & 31, c = rem >> 3, kb = rem & 7;
        const float* W = (m == 0) ? Wk1 : (m == 1) ? Wq1 : (m == 2) ? Wv1
                       : (m == 3) ? Wk2 : (m == 4) ? Wq2 : Wv2;
        int e  = c * 32 + (l & 31);
        int d0 = kb * 16 + (l >> 5) * 8;
        const float* src = W + e * 128 + d0;
        fa = *(const float4*)src;
        fb = *(const float4*)(src + 4);
        dst = wsb + (size_t)m * WSPROJ + (size_t)((c * 8 + kb) * 2) * 1024 + l * 16;
    } else if (bid < 256) {                // Wp1 [256][128]
        int idx = bid - 192, c = idx >> 3, kb = idx & 7;
        int e  = c * 32 + (l & 31);
        int d0 = kb * 16 + (l >> 5) * 8;
        const float* src = Wp1 + e * 128 + d0;
        fa = *(const float4*)src;
        fb = *(const float4*)(src + 4);
        dst = wsb + WP1OFF + (size_t)((c * 8 + kb) * 2) * 1024 + l * 16;
    } else {                               // Wp2 [10][256] -> 16x16 B-frags, cols 10..15 zero
        int kb = bid - 256;
        int a  = l & 15;
        int h0 = kb * 32 + ((l >> 4) & 3) * 8;
        if (a < 10) {
            const float* src = Wp2 + a * 256 + h0;
            fa = *(const float4*)src;
            fb = *(const float4*)(src + 4);
        }
        dst = wsb + WP2OFF + (size_t)(kb * 2) * 1024 + l * 16;
    }
    short8 hi, lo;
    split8(fa, fb, hi, lo);
    *(short8*)dst = hi;
    *(short8*)(dst + 1024) = lo;
}

// -------- main fused kernel: TWO batches per block, 8 waves, 2 blocks/CU --------
// A-fragments register-cached per blk (R12 lesson: LDS pipe was the shared
// bottleneck — 3x re-reads of A planes). 64-reg cache + ~56 base fits (512,4)
// 128-reg cap; spill tripwire = hbm_bytes >> 1.5e8.
__global__ __launch_bounds__(512, 4)
void fused_net(const float* __restrict__ states, const uint8_t* __restrict__ wsb,
               float* __restrict__ out_policy, float* __restrict__ out_w1,
               float* __restrict__ out_w2) {
    __shared__ __align__(16) char smem[65536];

    const int b2   = blockIdx.x;       // batch pair index
    const int t    = threadIdx.x;
    const int w    = t >> 6;           // 0..7
    const int l    = t & 63;
    const int l31  = l & 31;
    const int half = l >> 5;
    const int l15  = l & 15;
    const int g4   = (l >> 4) & 3;
    const int rh   = w >> 2;           // row-half 0/1
    const int c4   = w & 3;            // col-tile 0..3

    // ---- stage 2 batches of X into hi/lo planes, coalesced ----
    {
        const float* src = states + (size_t)b2 * 8192;
#pragma unroll
        for (int r = 0; r < 4; ++r) {
            int flat = (t + 512 * r) * 4;
            int n = flat >> 7, d0 = flat & 127;    // n 0..63
            float4 v = *(const float4*)(src + flat);
            uint32_t b0 = __float_as_uint(v.x), b1 = __float_as_uint(v.y);
            uint32_t b2u = __float_as_uint(v.z), b3 = __float_as_uint(v.w);
            float r0 = v.x - __uint_as_float(b0 & 0xFFFF0000u);
            float r1 = v.y - __uint_as_float(b1 & 0xFFFF0000u);
            float r2 = v.z - __uint_as_float(b2u & 0xFFFF0000u);
            float r3 = v.w - __uint_as_float(b3 & 0xFFFF0000u);
            uint2 hw, lw;
            hw.x = __builtin_amdgcn_perm(b1, b0, 0x07060302u);
            hw.y = __builtin_amdgcn_perm(b3, b2u, 0x07060302u);
            lw.x = __builtin_amdgcn_perm(__float_as_uint(r1), __float_as_uint(r0), 0x07060302u);
            lw.y = __builtin_amdgcn_perm(__float_as_uint(r3), __float_as_uint(r2), 0x07060302u);
            *(uint2*)(smem + pl_addr(AH_OFF, n, d0)) = hw;
            *(uint2*)(smem + pl_addr(AL_OFF, n, d0)) = lw;
        }
    }
    __syncthreads();

#pragma unroll 1
    for (int blk = 0; blk < 2; ++blk) {
        const uint8_t* wb = wsb + (size_t)(blk * 3) * WSPROJ;

        // ---- A-cache fill ONCE, then K, V, Q gemms reuse it (no LDS A-reads) ----
        U4 ahr[8], alr[8];
        fill_a(smem, rh * 32, l, ahr, alr);
        {
            f32x16 a = gemm32c(ahr, alr, wb + 0 * WSPROJ, c4, l);   // K
            store_plane32(smem, KB_OFF, rh * 32, c4, l, a);
        }
        __builtin_amdgcn_sched_barrier(0);
        {
            f32x16 a = gemm32c(ahr, alr, wb + 2 * WSPROJ, c4, l);   // V -> 1-term VT
            const int e = c4 * 32 + l31;
#pragma unroll
            for (int g = 0; g < 4; ++g) {                           // merged b64 stores
                int m0 = rh * 32 + 8 * g + 4 * half;
                uint2 pk;
                pk.x = (uint32_t)f2bf_rne(a[4 * g])     | ((uint32_t)f2bf_rne(a[4 * g + 1]) << 16);
                pk.y = (uint32_t)f2bf_rne(a[4 * g + 2]) | ((uint32_t)f2bf_rne(a[4 * g + 3]) << 16);
                *(uint2*)(smem + vt_addr(e, m0)) = pk;
            }
        }
        __builtin_amdgcn_sched_barrier(0);
        {
            f32x16 q = gemm32c(ahr, alr, wb + 1 * WSPROJ, c4, l);   // Q
            __syncthreads();                        // all fills/reads done; K/V visible
            store_plane32(smem, AL_OFF, rh * 32, c4, l, q);         // Q into dead X-lo
        }
        __builtin_amdgcn_sched_barrier(0);
        __syncthreads();                            // Q visible

        // ---- S = (Q K^T)*inv_scale: 8 16x16 tiles, one per wave ----
        {
            const int bq = w >> 2, rb = (w >> 1) & 1, mb = w & 1;
            const int qrow = bq * 32 + rb * 16 + l15;
            const int krow = bq * 32 + mb * 16 + l15;
            f32x4 s4 = {0.f, 0.f, 0.f, 0.f};
#pragma unroll
            for (int kb = 0; kb < 4; ++kb) {
                int e0 = kb * 32 + g4 * 8;
                U4 qh, kh;
                qh.q = *(const uint4*)(smem + pl_addr(AL_OFF, qrow, e0));
                kh.q = *(const uint4*)(smem + pl_addr(KB_OFF, krow, e0));
                s4 = __builtin_amdgcn_mfma_f32_16x16x32_bf16(qh.s8, kh.s8, s4, 0, 0, 0);
            }
            __syncthreads();                        // all K/Q reads done (S aliases KB)
#pragma unroll
            for (int r = 0; r < 4; ++r) {
                int n = bq * 32 + rb * 16 + g4 * 4 + r;    // verified 16x16 D mapping
                *(float*)(smem + s_addr(n, mb * 16 + l15)) = s4[r] * INV_SCALE;
            }
        }
        __syncthreads();

        // ---- softmax over m: 128 row-halves on waves 0-1 ----
        if (t < 128) {
            const int n = w * 32 + l31;            // w in {0,1} here
            float4 v0 = *(const float4*)(smem + s_addr(n, half * 16));
            float4 v1 = *(const float4*)(smem + s_addr(n, half * 16 + 4));
            float4 v2 = *(const float4*)(smem + s_addr(n, half * 16 + 8));
            float4 v3 = *(const float4*)(smem + s_addr(n, half * 16 + 12));
            float vv[16] = {v0.x, v0.y, v0.z, v0.w, v1.x, v1.y, v1.z, v1.w,
                            v2.x, v2.y, v2.z, v2.w, v3.x, v3.y, v3.z, v3.w};
            float mx = vv[0];
#pragma unroll
            for (int i = 1; i < 16; ++i) mx = fmaxf(mx, vv[i]);
            mx = fmaxf(mx, __shfl_xor(mx, 32));
            float sum = 0.f;
#pragma unroll
            for (int i = 0; i < 16; ++i) { vv[i] = __expf(vv[i] - mx); sum += vv[i]; }
            sum += __shfl_xor(sum, 32);
            float inv = 1.0f / sum;
#pragma unroll
            for (int i = 0; i < 16; ++i) vv[i] *= inv;
            *(float4*)(smem + s_addr(n, half * 16))      = make_float4(vv[0], vv[1], vv[2], vv[3]);
            *(float4*)(smem + s_addr(n, half * 16 + 4))  = make_float4(vv[4], vv[5], vv[6], vv[7]);
            *(float4*)(smem + s_addr(n, half * 16 + 8))  = make_float4(vv[8], vv[9], vv[10], vv[11]);
            *(float4*)(smem + s_addr(n, half * 16 + 12)) = make_float4(vv[12], vv[13], vv[14], vv[15]);
        }
        __syncthreads();

        // ---- attention-weight output for both batches (coalesced, 1 float4/thread) ----
        {
            float* outw = blk ? out_w2 : out_w1;
            int f = t * 4;                          // 0..2047
            int n = f >> 5, m0 = f & 31;
            float4 o = *(const float4*)(smem + s_addr(n, m0));
            *(float4*)(outw + (size_t)b2 * 2048 + f) = o;
        }

        // ---- PV: 8 tiles (bq, c4): ACT'[n][e] = sum_m P[n][m] V[m][e] ----
        {
            const int bq = w >> 2;
            f32x16 pv = {0.f,0.f,0.f,0.f, 0.f,0.f,0.f,0.f, 0.f,0.f,0.f,0.f, 0.f,0.f,0.f,0.f};
            const int e = c4 * 32 + l31;
#pragma unroll
            for (int kb = 0; kb < 2; ++kb) {
                int m0 = kb * 16 + half * 8;
                float4 fa = *(const float4*)(smem + s_addr(bq * 32 + l31, m0));
                float4 fb = *(const float4*)(smem + s_addr(bq * 32 + l31, m0 + 4));
                short8 wh, wl;
                split8(fa, fb, wh, wl);
                U4 vh;
                vh.q = *(const uint4*)(smem + vt_addr(e, bq * 32 + m0));
                pv = __builtin_amdgcn_mfma_f32_32x32x16_bf16(wh, vh.s8, pv, 0, 0, 0);
                pv = __builtin_amdgcn_mfma_f32_32x32x16_bf16(wl, vh.s8, pv, 0, 0, 0);
            }
            store_act32(smem, bq * 32, c4, l, pv);
        }
        __builtin_amdgcn_sched_barrier(0);
        __syncthreads();
    }

    // ---- MLP hidden: A-cache NF once, 2 reps; H -> bf16 over dead KB+VT ----
    {
        U4 ahr[8], alr[8];
        fill_a(smem, rh * 32, l, ahr, alr);
#pragma unroll 1
        for (int rep = 0; rep < 2; ++rep) {
            const int hc = c4 + rep * 4;
            f32x16 a = gemm32c(ahr, alr, wsb + WP1OFF, hc, l);
            const int hcol = hc * 32 + l31;
#pragma unroll
            for (int r = 0; r < 16; ++r) {
                int n = rh * 32 + (r & 3) + 8 * (r >> 2) + 4 * half;
                float x = a[r];
                x = fmaxf(x, 0.01f * x);            // leaky_relu
                *(uint16_t*)(smem + h_addr(n, hcol)) = f2bf_rne(x);
            }
            __builtin_amdgcn_sched_barrier(0);
        }
    }
    __syncthreads();

    // ---- policy logits: 4x 16x16 tiles (waves 0-3), K=256; logits -> dead AH ----
    if (w < 4) {
        f32x4 acc = {0.f, 0.f, 0.f, 0.f};
        const int n = w * 16 + l15;                 // rows 0..63
#pragma unroll
        for (int kb = 0; kb < 8; ++kb) {
            int h0 = kb * 32 + g4 * 8;
            U4 a;
            a.q = *(const uint4*)(smem + h_addr(n, h0));
            const uint8_t* p = wsb + WP2OFF + (size_t)(kb * 2) * 1024 + (size_t)l * 16;
            U4 bh, bl;
            bh.q = *(const uint4*)p;
            bl.q = *(const uint4*)(p + 1024);
            acc = __builtin_amdgcn_mfma_f32_16x16x32_bf16(a.s8, bh.s8, acc, 0, 0, 0);
            acc = __builtin_amdgcn_mfma_f32_16x16x32_bf16(a.s8, bl.s8, acc, 0, 0, 0);
        }
#pragma unroll
        for (int r = 0; r < 4; ++r) {
            int nn = w * 16 + g4 * 4 + r;
            *(float*)(smem + ps_addr(nn, l15)) = acc[r];
        }
    }
    __syncthreads();

    // ---- policy softmax over 10 actions (64 rows, wave 0) ----
    if (t < 64) {
        float v[10];
#pragma unroll
        for (int a2 = 0; a2 < 10; ++a2) v[a2] = *(const float*)(smem + ps_addr(t, a2));
        float mx = v[0];
#pragma unroll
        for (int a2 = 1; a2 < 10; ++a2) mx = fmaxf(mx, v[a2]);
        float sum = 0.f;
#pragma unroll
        for (int a2 = 0; a2 < 10; ++a2) { v[a2] = __expf(v[a2] - mx); sum += v[a2]; }
        float inv = 1.0f / sum;
#pragma unroll
        for (int a2 = 0; a2 < 10; ++a2) *(float*)(smem + ps_addr(t, a2)) = v[a2] * inv;
    }
    __syncthreads();

    for (int o = t; o < 640; o += 512) {
        int n = o / 10, a2 = o - n * 10;
        out_policy[(size_t)b2 * 640 + o] = *(const float*)(smem + ps_addr(n, a2));
    }
}

}  // namespace

extern "C" void kernel_launch(void* const* d_in, const int* in_sizes, int n_in,
                              void* d_out, int out_size, void* d_ws, size_t ws_size,
                              hipStream_t stream) {
    const float* states = (const float*)d_in[0];
    const float* Wk1 = (const float*)d_in[1];
    const float* Wq1 = (const float*)d_in[2];
    const float* Wv1 = (const float*)d_in[3];
    const float* Wk2 = (const float*)d_in[4];
    const float* Wq2 = (const float*)d_in[5];
    const float* Wv2 = (const float*)d_in[6];
    const float* Wp1 = (const float*)d_in[7];
    const float* Wp2 = (const float*)d_in[8];

    const int B = in_sizes[0] / 4096;   // 8192 batches

    uint8_t* wsb = (uint8_t*)d_ws;      // needs ~541 KB
    float* out        = (float*)d_out;
    float* out_policy = out;
    float* out_w1     = out_policy + (size_t)B * 320;
    float* out_w2     = out_w1 + (size_t)B * 1024;

    hipLaunchKernelGGL(prepack, dim3(264), dim3(64), 0, stream,
                       Wk1, Wq1, Wv1, Wk2, Wq2, Wv2, Wp1, Wp2, wsb);
    hipLaunchKernelGGL(fused_net, dim3(B / 2), dim3(512), 0, stream,
                       states, wsb, out_policy, out_w1, out_w2);
}

// Round 14
// 260.798 us; speedup vs baseline: 1.2814x; 1.2814x over previous
//
#include <hip/hip_runtime.h>
#include <stdint.h>

namespace {

typedef __attribute__((ext_vector_type(8)))  short short8;   // 8 bf16
typedef __attribute__((ext_vector_type(16))) float f32x16;
typedef __attribute__((ext_vector_type(4)))  float f32x4;

union U4 {
    uint4    q;
    uint32_t u[4];
    uint16_t us[8];
    short8   s8;
};

constexpr float INV_SCALE = 0.08838834764831845f;  // 1/sqrt(128), BOTH attn blocks

// ---- workspace (weight fragment) layout, bytes (prepack UNCHANGED) ----
constexpr size_t WSPROJ = 65536;            // 4c*8kb*2(hi,lo)*1024
constexpr size_t WP1OFF = 6 * WSPROJ;       // Wp1: c=0..7, kb=0..7 -> 131072 B
constexpr size_t WP2OFF = WP1OFF + 131072;  // Wp2 (16x16 frags): kb=0..7 -> 16384 B

// ---- LDS arena: 65536 B, TWO batches row-stacked (64 rows), 2 blocks/CU ----
constexpr int AH_OFF = 0;       // X/WAV/NF hi plane bf16 [64][128], swizzled, 16KB
constexpr int AL_OFF = 16384;   // X/WAV/NF lo plane 16KB; Q plane ALIASES (X-lo dead post-proj)
constexpr int KB_OFF = 32768;   // K plane bf16 [64][128] 16KB; S fp32 [64][36dw] aliases post-S-read
constexpr int VT_OFF = 49152;   // V 1-term RNE plane [128 e][64 m] bf16, swizzled, 16KB
// H bf16 [64][256] (32KB) aliases KB+VT at MLP time; policy logits alias AH.

__device__ __forceinline__ int pl_addr(int base, int n, int e) {   // bf16 plane [64][128]
    return base + ((n * 256 + e * 2) ^ ((n & 15) << 4));
}
__device__ __forceinline__ int vt_addr(int e, int m) {             // bf16 [128][64]
    return VT_OFF + ((e * 128 + m * 2) ^ ((e & 7) << 4));
}
__device__ __forceinline__ int s_addr(int n, int m) {              // fp32 [64][36dw], over KB
    return KB_OFF + n * 144 + m * 4;
}
__device__ __forceinline__ int h_addr(int n, int h) {              // bf16 [64][256], over KB+VT
    return KB_OFF + ((n * 512 + h * 2) ^ ((n & 15) << 4));
}
__device__ __forceinline__ int ps_addr(int n, int a) {             // fp32 [64][36dw], over AH
    return AH_OFF + n * 144 + a * 4;
}

__device__ __forceinline__ uint16_t f2bf_rne(float x) {
    uint32_t u = __float_as_uint(x);
    u += 0x7FFFu + ((u >> 16) & 1u);
    return (uint16_t)(u >> 16);
}

// split 8 fp32 -> (hi bf16x8, lo bf16x8); hi = trunc, lo = trunc(x - hi)
__device__ __forceinline__ void split8(float4 a, float4 b, short8& hi, short8& lo) {
    float xs[8] = {a.x, a.y, a.z, a.w, b.x, b.y, b.z, b.w};
    U4 h, l;
#pragma unroll
    for (int p = 0; p < 4; ++p) {
        uint32_t b0 = __float_as_uint(xs[2 * p]);
        uint32_t b1 = __float_as_uint(xs[2 * p + 1]);
        float r0 = xs[2 * p]     - __uint_as_float(b0 & 0xFFFF0000u);
        float r1 = xs[2 * p + 1] - __uint_as_float(b1 & 0xFFFF0000u);
        h.u[p] = __builtin_amdgcn_perm(b1, b0, 0x07060302u);
        l.u[p] = __builtin_amdgcn_perm(__float_as_uint(r1), __float_as_uint(r0), 0x07060302u);
    }
    hi = h.s8; lo = l.s8;
}

// FUSED K/V/Q projection: one kb-loop, A loaded ONCE per kb and fed to all three
// B matrices (R12 lesson: LDS pipe saturated by 3x A re-reads; R13 lesson: no
// persistent A cache — it spills under the 128-reg cap). 3 accs = 48 regs.
__device__ __forceinline__ void gemm_kvq(const char* smem, const uint8_t* __restrict__ wb,
                                         int rowoff, int c, int l,
                                         f32x16& kacc, f32x16& vacc, f32x16& qacc) {
    f32x16 z = {0.f,0.f,0.f,0.f, 0.f,0.f,0.f,0.f, 0.f,0.f,0.f,0.f, 0.f,0.f,0.f,0.f};
    kacc = z; vacc = z; qacc = z;
    const int n = rowoff + (l & 31), half = l >> 5;
#pragma unroll 1
    for (int kb = 0; kb < 8; ++kb) {
        const int d0 = kb * 16 + half * 8;
        U4 ah, al;
        ah.q = *(const uint4*)(smem + pl_addr(AH_OFF, n, d0));
        al.q = *(const uint4*)(smem + pl_addr(AL_OFF, n, d0));
        const uint8_t* p = wb + (size_t)((c * 8 + kb) * 2) * 1024 + (size_t)l * 16;
        U4 bh, bl;
        bh.q = *(const uint4*)p;                          // K hi/lo
        bl.q = *(const uint4*)(p + 1024);
        kacc = __builtin_amdgcn_mfma_f32_32x32x16_bf16(ah.s8, bh.s8, kacc, 0, 0, 0);
        kacc = __builtin_amdgcn_mfma_f32_32x32x16_bf16(al.s8, bh.s8, kacc, 0, 0, 0);
        kacc = __builtin_amdgcn_mfma_f32_32x32x16_bf16(ah.s8, bl.s8, kacc, 0, 0, 0);
        bh.q = *(const uint4*)(p + WSPROJ);               // Q hi/lo
        bl.q = *(const uint4*)(p + WSPROJ + 1024);
        qacc = __builtin_amdgcn_mfma_f32_32x32x16_bf16(ah.s8, bh.s8, qacc, 0, 0, 0);
        qacc = __builtin_amdgcn_mfma_f32_32x32x16_bf16(al.s8, bh.s8, qacc, 0, 0, 0);
        qacc = __builtin_amdgcn_mfma_f32_32x32x16_bf16(ah.s8, bl.s8, qacc, 0, 0, 0);
        bh.q = *(const uint4*)(p + 2 * WSPROJ);           // V hi/lo
        bl.q = *(const uint4*)(p + 2 * WSPROJ + 1024);
        vacc = __builtin_amdgcn_mfma_f32_32x32x16_bf16(ah.s8, bh.s8, vacc, 0, 0, 0);
        vacc = __builtin_amdgcn_mfma_f32_32x32x16_bf16(al.s8, bh.s8, vacc, 0, 0, 0);
        vacc = __builtin_amdgcn_mfma_f32_32x32x16_bf16(ah.s8, bl.s8, vacc, 0, 0, 0);
    }
}

// FUSED MLP (both col-reps): A loaded once per kb, 2 accs.
__device__ __forceinline__ void gemm_mlp2(const char* smem, const uint8_t* __restrict__ mb,
                                          int rowoff, int c, int l,
                                          f32x16& a0, f32x16& a1) {
    f32x16 z = {0.f,0.f,0.f,0.f, 0.f,0.f,0.f,0.f, 0.f,0.f,0.f,0.f, 0.f,0.f,0.f,0.f};
    a0 = z; a1 = z;
    const int n = rowoff + (l & 31), half = l >> 5;
#pragma unroll 1
    for (int kb = 0; kb < 8; ++kb) {
        const int d0 = kb * 16 + half * 8;
        U4 ah, al;
        ah.q = *(const uint4*)(smem + pl_addr(AH_OFF, n, d0));
        al.q = *(const uint4*)(smem + pl_addr(AL_OFF, n, d0));
        const uint8_t* p0 = mb + (size_t)((c * 8 + kb) * 2) * 1024 + (size_t)l * 16;
        const uint8_t* p1 = mb + (size_t)(((c + 4) * 8 + kb) * 2) * 1024 + (size_t)l * 16;
        U4 bh, bl;
        bh.q = *(const uint4*)p0;
        bl.q = *(const uint4*)(p0 + 1024);
        a0 = __builtin_amdgcn_mfma_f32_32x32x16_bf16(ah.s8, bh.s8, a0, 0, 0, 0);
        a0 = __builtin_amdgcn_mfma_f32_32x32x16_bf16(al.s8, bh.s8, a0, 0, 0, 0);
        a0 = __builtin_amdgcn_mfma_f32_32x32x16_bf16(ah.s8, bl.s8, a0, 0, 0, 0);
        bh.q = *(const uint4*)p1;
        bl.q = *(const uint4*)(p1 + 1024);
        a1 = __builtin_amdgcn_mfma_f32_32x32x16_bf16(ah.s8, bh.s8, a1, 0, 0, 0);
        a1 = __builtin_amdgcn_mfma_f32_32x32x16_bf16(al.s8, bh.s8, a1, 0, 0, 0);
        a1 = __builtin_amdgcn_mfma_f32_32x32x16_bf16(ah.s8, bl.s8, a1, 0, 0, 0);
    }
}

// store 32x32 D-tile as 1-term RNE bf16 plane at row offset
__device__ __forceinline__ void store_plane32(char* smem, int base, int rowoff, int c, int l,
                                              const f32x16& a) {
    const int e = c * 32 + (l & 31);
    const int half = l >> 5;
#pragma unroll
    for (int r = 0; r < 16; ++r) {
        int n = rowoff + (r & 3) + 8 * (r >> 2) + 4 * half;   // verified 32x32 D mapping
        *(uint16_t*)(smem + pl_addr(base, n, e)) = f2bf_rne(a[r]);
    }
}

// store 32x32 D-tile as hi/lo trunc-split ACT planes at row offset
__device__ __forceinline__ void store_act32(char* smem, int rowoff, int c, int l, const f32x16& a) {
    const int e = c * 32 + (l & 31);
    const int half = l >> 5;
#pragma unroll
    for (int r = 0; r < 16; ++r) {
        int n = rowoff + (r & 3) + 8 * (r >> 2) + 4 * half;
        uint32_t bu = __float_as_uint(a[r]);
        float rr = a[r] - __uint_as_float(bu & 0xFFFF0000u);
        *(uint16_t*)(smem + pl_addr(AH_OFF, n, e)) = (uint16_t)(bu >> 16);
        *(uint16_t*)(smem + pl_addr(AL_OFF, n, e)) = (uint16_t)(__float_as_uint(rr) >> 16);
    }
}

// -------- pre-pass: convert weights to fragment-ordered split-bf16 in d_ws --------
__global__ void prepack(const float* __restrict__ Wk1, const float* __restrict__ Wq1,
                        const float* __restrict__ Wv1, const float* __restrict__ Wk2,
                        const float* __restrict__ Wq2, const float* __restrict__ Wv2,
                        const float* __restrict__ Wp1, const float* __restrict__ Wp2,
                        uint8_t* __restrict__ wsb) {
    const int bid = blockIdx.x;
    const int l = threadIdx.x;
    float4 fa = make_float4(0.f, 0.f, 0.f, 0.f), fb = fa;
    uint8_t* dst;
    if (bid < 192) {                       // 6 proj matrices, 32x32 B-frags
        int m = bid >> 5, rem = bid & 31, c = rem >> 3, kb = rem & 7;
        const float* W = (m == 0) ? Wk1 : (m == 1) ? Wq1 : (m == 2) ? Wv1
                       : (m == 3) ? Wk2 : (m == 4) ? Wq2 : Wv2;
        int e  = c * 32 + (l & 31);
        int d0 = kb * 16 + (l >> 5) * 8;
        const float* src = W + e * 128 + d0;
        fa = *(const float4*)src;
        fb = *(const float4*)(src + 4);
        dst = wsb + (size_t)m * WSPROJ + (size_t)((c * 8 + kb) * 2) * 1024 + l * 16;
    } else if (bid < 256) {                // Wp1 [256][128]
        int idx = bid - 192, c = idx >> 3, kb = idx & 7;
        int e  = c * 32 + (l & 31);
        int d0 = kb * 16 + (l >> 5) * 8;
        const float* src = Wp1 + e * 128 + d0;
        fa = *(const float4*)src;
        fb = *(const float4*)(src + 4);
        dst = wsb + WP1OFF + (size_t)((c * 8 + kb) * 2) * 1024 + l * 16;
    } else {                               // Wp2 [10][256] -> 16x16 B-frags, cols 10..15 zero
        int kb = bid - 256;
        int a  = l & 15;
        int h0 = kb * 32 + ((l >> 4) & 3) * 8;
        if (a < 10) {
            const float* src = Wp2 + a * 256 + h0;
            fa = *(const float4*)src;
            fb = *(const float4*)(src + 4);
        }
        dst = wsb + WP2OFF + (size_t)(kb * 2) * 1024 + l * 16;
    }
    short8 hi, lo;
    split8(fa, fb, hi, lo);
    *(short8*)dst = hi;
    *(short8*)(dst + 1024) = lo;
}

// -------- main fused kernel: TWO batches per block, 8 waves, 2 blocks/CU --------
// Fused-consumer gemms (KVQ / MLP2) read each A-fragment from LDS exactly once.
// Live set ~105 regs < (512,4) 128-reg cap; spill tripwire = WRITE_SIZE >> 76MB.
__global__ __launch_bounds__(512, 4)
void fused_net(const float* __restrict__ states, const uint8_t* __restrict__ wsb,
               float* __restrict__ out_policy, float* __restrict__ out_w1,
               float* __restrict__ out_w2) {
    __shared__ __align__(16) char smem[65536];

    const int b2   = blockIdx.x;       // batch pair index
    const int t    = threadIdx.x;
    const int w    = t >> 6;           // 0..7
    const int l    = t & 63;
    const int l31  = l & 31;
    const int half = l >> 5;
    const int l15  = l & 15;
    const int g4   = (l >> 4) & 3;
    const int rh   = w >> 2;           // row-half 0/1
    const int c4   = w & 3;            // col-tile 0..3

    // ---- stage 2 batches of X into hi/lo planes, coalesced ----
    {
        const float* src = states + (size_t)b2 * 8192;
#pragma unroll
        for (int r = 0; r < 4; ++r) {
            int flat = (t + 512 * r) * 4;
            int n = flat >> 7, d0 = flat & 127;    // n 0..63
            float4 v = *(const float4*)(src + flat);
            uint32_t b0 = __float_as_uint(v.x), b1 = __float_as_uint(v.y);
            uint32_t b2u = __float_as_uint(v.z), b3 = __float_as_uint(v.w);
            float r0 = v.x - __uint_as_float(b0 & 0xFFFF0000u);
            float r1 = v.y - __uint_as_float(b1 & 0xFFFF0000u);
            float r2 = v.z - __uint_as_float(b2u & 0xFFFF0000u);
            float r3 = v.w - __uint_as_float(b3 & 0xFFFF0000u);
            uint2 hw, lw;
            hw.x = __builtin_amdgcn_perm(b1, b0, 0x07060302u);
            hw.y = __builtin_amdgcn_perm(b3, b2u, 0x07060302u);
            lw.x = __builtin_amdgcn_perm(__float_as_uint(r1), __float_as_uint(r0), 0x07060302u);
            lw.y = __builtin_amdgcn_perm(__float_as_uint(r3), __float_as_uint(r2), 0x07060302u);
            *(uint2*)(smem + pl_addr(AH_OFF, n, d0)) = hw;
            *(uint2*)(smem + pl_addr(AL_OFF, n, d0)) = lw;
        }
    }
    __syncthreads();

#pragma unroll 1
    for (int blk = 0; blk < 2; ++blk) {
        const uint8_t* wb = wsb + (size_t)(blk * 3) * WSPROJ;

        // ---- FUSED projections: A read once; K,V stored now, Q after barrier ----
        {
            f32x16 kacc, vacc, qacc;
            gemm_kvq(smem, wb, rh * 32, c4, l, kacc, vacc, qacc);
            store_plane32(smem, KB_OFF, rh * 32, c4, l, kacc);
            const int e = c4 * 32 + l31;
#pragma unroll
            for (int g = 0; g < 4; ++g) {                           // V merged b64 stores
                int m0 = rh * 32 + 8 * g + 4 * half;
                uint2 pk;
                pk.x = (uint32_t)f2bf_rne(vacc[4 * g])     | ((uint32_t)f2bf_rne(vacc[4 * g + 1]) << 16);
                pk.y = (uint32_t)f2bf_rne(vacc[4 * g + 2]) | ((uint32_t)f2bf_rne(vacc[4 * g + 3]) << 16);
                *(uint2*)(smem + vt_addr(e, m0)) = pk;
            }
            __syncthreads();                        // all A reads done; K/V visible
            store_plane32(smem, AL_OFF, rh * 32, c4, l, qacc);      // Q into dead X-lo
        }
        __builtin_amdgcn_sched_barrier(0);
        __syncthreads();                            // Q visible

        // ---- S = (Q K^T)*inv_scale: 8 16x16 tiles, one per wave ----
        {
            const int bq = w >> 2, rb = (w >> 1) & 1, mb = w & 1;
            const int qrow = bq * 32 + rb * 16 + l15;
            const int krow = bq * 32 + mb * 16 + l15;
            f32x4 s4 = {0.f, 0.f, 0.f, 0.f};
#pragma unroll
            for (int kb = 0; kb < 4; ++kb) {
                int e0 = kb * 32 + g4 * 8;
                U4 qh, kh;
                qh.q = *(const uint4*)(smem + pl_addr(AL_OFF, qrow, e0));
                kh.q = *(const uint4*)(smem + pl_addr(KB_OFF, krow, e0));
                s4 = __builtin_amdgcn_mfma_f32_16x16x32_bf16(qh.s8, kh.s8, s4, 0, 0, 0);
            }
            __syncthreads();                        // all K/Q reads done (S aliases KB)
#pragma unroll
            for (int r = 0; r < 4; ++r) {
                int n = bq * 32 + rb * 16 + g4 * 4 + r;    // verified 16x16 D mapping
                *(float*)(smem + s_addr(n, mb * 16 + l15)) = s4[r] * INV_SCALE;
            }
        }
        __syncthreads();

        // ---- softmax over m: 128 row-halves on waves 0-1 ----
        if (t < 128) {
            const int n = w * 32 + l31;            // w in {0,1} here
            float4 v0 = *(const float4*)(smem + s_addr(n, half * 16));
            float4 v1 = *(const float4*)(smem + s_addr(n, half * 16 + 4));
            float4 v2 = *(const float4*)(smem + s_addr(n, half * 16 + 8));
            float4 v3 = *(const float4*)(smem + s_addr(n, half * 16 + 12));
            float vv[16] = {v0.x, v0.y, v0.z, v0.w, v1.x, v1.y, v1.z, v1.w,
                            v2.x, v2.y, v2.z, v2.w, v3.x, v3.y, v3.z, v3.w};
            float mx = vv[0];
#pragma unroll
            for (int i = 1; i < 16; ++i) mx = fmaxf(mx, vv[i]);
            mx = fmaxf(mx, __shfl_xor(mx, 32));
            float sum = 0.f;
#pragma unroll
            for (int i = 0; i < 16; ++i) { vv[i] = __expf(vv[i] - mx); sum += vv[i]; }
            sum += __shfl_xor(sum, 32);
            float inv = 1.0f / sum;
#pragma unroll
            for (int i = 0; i < 16; ++i) vv[i] *= inv;
            *(float4*)(smem + s_addr(n, half * 16))      = make_float4(vv[0], vv[1], vv[2], vv[3]);
            *(float4*)(smem + s_addr(n, half * 16 + 4))  = make_float4(vv[4], vv[5], vv[6], vv[7]);
            *(float4*)(smem + s_addr(n, half * 16 + 8))  = make_float4(vv[8], vv[9], vv[10], vv[11]);
            *(float4*)(smem + s_addr(n, half * 16 + 12)) = make_float4(vv[12], vv[13], vv[14], vv[15]);
        }
        __syncthreads();

        // ---- attention-weight output for both batches (coalesced, 1 float4/thread) ----
        {
            float* outw = blk ? out_w2 : out_w1;
            int f = t * 4;                          // 0..2047
            int n = f >> 5, m0 = f & 31;
            float4 o = *(const float4*)(smem + s_addr(n, m0));
            *(float4*)(outw + (size_t)b2 * 2048 + f) = o;
        }

        // ---- PV: 8 tiles (bq, c4): ACT'[n][e] = sum_m P[n][m] V[m][e] ----
        {
            const int bq = w >> 2;
            f32x16 pv = {0.f,0.f,0.f,0.f, 0.f,0.f,0.f,0.f, 0.f,0.f,0.f,0.f, 0.f,0.f,0.f,0.f};
            const int e = c4 * 32 + l31;
#pragma unroll
            for (int kb = 0; kb < 2; ++kb) {
                int m0 = kb * 16 + half * 8;
                float4 fa = *(const float4*)(smem + s_addr(bq * 32 + l31, m0));
                float4 fb = *(const float4*)(smem + s_addr(bq * 32 + l31, m0 + 4));
                short8 wh, wl;
                split8(fa, fb, wh, wl);
                U4 vh;
                vh.q = *(const uint4*)(smem + vt_addr(e, bq * 32 + m0));
                pv = __builtin_amdgcn_mfma_f32_32x32x16_bf16(wh, vh.s8, pv, 0, 0, 0);
                pv = __builtin_amdgcn_mfma_f32_32x32x16_bf16(wl, vh.s8, pv, 0, 0, 0);
            }
            store_act32(smem, bq * 32, c4, l, pv);
        }
        __builtin_amdgcn_sched_barrier(0);
        __syncthreads();
    }

    // ---- MLP hidden (fused 2 reps, A read once); H -> bf16 over dead KB+VT ----
    {
        f32x16 h0_, h1_;
        gemm_mlp2(smem, wsb + WP1OFF, rh * 32, c4, l, h0_, h1_);
#pragma unroll
        for (int rep = 0; rep < 2; ++rep) {
            const int hc = c4 + rep * 4;
            const int hcol = hc * 32 + l31;
#pragma unroll
            for (int r = 0; r < 16; ++r) {
                int n = rh * 32 + (r & 3) + 8 * (r >> 2) + 4 * half;
                float x = rep ? h1_[r] : h0_[r];
                x = fmaxf(x, 0.01f * x);            // leaky_relu
                *(uint16_t*)(smem + h_addr(n, hcol)) = f2bf_rne(x);
            }
        }
    }
    __syncthreads();

    // ---- policy logits: 4x 16x16 tiles (waves 0-3), K=256; logits -> dead AH ----
    if (w < 4) {
        f32x4 acc = {0.f, 0.f, 0.f, 0.f};
        const int n = w * 16 + l15;                 // rows 0..63
#pragma unroll
        for (int kb = 0; kb < 8; ++kb) {
            int h0 = kb * 32 + g4 * 8;
            U4 a;
            a.q = *(const uint4*)(smem + h_addr(n, h0));
            const uint8_t* p = wsb + WP2OFF + (size_t)(kb * 2) * 1024 + (size_t)l * 16;
            U4 bh, bl;
            bh.q = *(const uint4*)p;
            bl.q = *(const uint4*)(p + 1024);
            acc = __builtin_amdgcn_mfma_f32_16x16x32_bf16(a.s8, bh.s8, acc, 0, 0, 0);
            acc = __builtin_amdgcn_mfma_f32_16x16x32_bf16(a.s8, bl.s8, acc, 0, 0, 0);
        }
#pragma unroll
        for (int r = 0; r < 4; ++r) {
            int nn = w * 16 + g4 * 4 + r;
            *(float*)(smem + ps_addr(nn, l15)) = acc[r];
        }
    }
    __syncthreads();

    // ---- policy softmax over 10 actions (64 rows, wave 0) ----
    if (t < 64) {
        float v[10];
#pragma unroll
        for (int a2 = 0; a2 < 10; ++a2) v[a2] = *(const float*)(smem + ps_addr(t, a2));
        float mx = v[0];
#pragma unroll
        for (int a2 = 1; a2 < 10; ++a2) mx = fmaxf(mx, v[a2]);
        float sum = 0.f;
#pragma unroll
        for (int a2 = 0; a2 < 10; ++a2) { v[a2] = __expf(v[a2] - mx); sum += v[a2]; }
        float inv = 1.0f / sum;
#pragma unroll
        for (int a2 = 0; a2 < 10; ++a2) *(float*)(smem + ps_addr(t, a2)) = v[a2] * inv;
    }
    __syncthreads();

    for (int o = t; o < 640; o += 512) {
        int n = o / 10, a2 = o - n * 10;
        out_policy[(size_t)b2 * 640 + o] = *(const float*)(smem + ps_addr(n, a2));
    }
}

}  // namespace

extern "C" void kernel_launch(void* const* d_in, const int* in_sizes, int n_in,
                              void* d_out, int out_size, void* d_ws, size_t ws_size,
                              hipStream_t stream) {
    const float* states = (const float*)d_in[0];
    const float* Wk1 = (const float*)d_in[1];
    const float* Wq1 = (const float*)d_in[2];
    const float* Wv1 = (const float*)d_in[3];
    const float* Wk2 = (const float*)d_in[4];
    const float* Wq2 = (const float*)d_in[5];
    const float* Wv2 = (const float*)d_in[6];
    const float* Wp1 = (const float*)d_in[7];
    const float* Wp2 = (const float*)d_in[8];

    const int B = in_sizes[0] / 4096;   // 8192 batches

    uint8_t* wsb = (uint8_t*)d_ws;      // needs ~541 KB
    float* out        = (float*)d_out;
    float* out_policy = out;
    float* out_w1     = out_policy + (size_t)B * 320;
    float* out_w2     = out_w1 + (size_t)B * 1024;

    hipLaunchKernelGGL(prepack, dim3(264), dim3(64), 0, stream,
                       Wk1, Wq1, Wv1, Wk2, Wq2, Wv2, Wp1, Wp2, wsb);
    hipLaunchKernelGGL(fused_net, dim3(B / 2), dim3(512), 0, stream,
                       states, wsb, out_policy, out_w1, out_w2);
}

// Round 15
// 220.660 us; speedup vs baseline: 1.5145x; 1.1819x over previous
//
#include <hip/hip_runtime.h>
#include <stdint.h>

namespace {

typedef __attribute__((ext_vector_type(8)))  short short8;   // 8 bf16
typedef __attribute__((ext_vector_type(16))) float f32x16;
typedef __attribute__((ext_vector_type(4)))  float f32x4;

union U4 {
    uint4    q;
    uint32_t u[4];
    uint16_t us[8];
    short8   s8;
};

constexpr float INV_SCALE = 0.08838834764831845f;  // 1/sqrt(128), BOTH attn blocks

// ---- workspace layout, bytes ----
// frag slots: [M1, V1, M2, V2] (M = Wq^T*Wk folded QK matrix), then Wp1, Wp2,
// then fp32 scratch for M1/M2 (written by prep_m, fragment-packed by prepack).
constexpr size_t WSPROJ  = 65536;             // 4c*8kb*2(hi,lo)*1024
constexpr size_t WP1OFF  = 4 * WSPROJ;        // 262144
constexpr size_t WP2OFF  = WP1OFF + 131072;   // 393216
constexpr size_t M1F_OFF = WP2OFF + 16384;    // 409600 (fp32 128x128)
constexpr size_t M2F_OFF = M1F_OFF + 65536;   // 475136; end 540672

// ---- LDS arena: 74752 B (2 blocks/CU: 149.5KB <= 160KB) ----
constexpr int AH_OFF = 0;       // X/WAV/NF hi plane bf16 [64][128], swizzled, 16KB
constexpr int AL_OFF = 16384;   // X/WAV/NF lo plane, 16KB
constexpr int TB_OFF = 32768;   // T = X*M, 1-term RNE plane [64][128], 16KB
constexpr int VT_OFF = 49152;   // V 1-term RNE plane [128 e][64 m] bf16, 16KB
constexpr int S_OFF  = 65536;   // DEDICATED S fp32 [64][36dw], 9216B (no alias barrier)
// H bf16 [64][256] (32KB) aliases TB+VT at MLP time; policy logits alias AH.

__device__ __forceinline__ int pl_addr(int base, int n, int e) {   // bf16 plane [64][128]
    return base + ((n * 256 + e * 2) ^ ((n & 15) << 4));
}
__device__ __forceinline__ int vt_addr(int e, int m) {             // bf16 [128][64]
    return VT_OFF + ((e * 128 + m * 2) ^ ((e & 7) << 4));
}
__device__ __forceinline__ int s_addr(int n, int m) {              // fp32 [64][36dw]
    return S_OFF + n * 144 + m * 4;
}
__device__ __forceinline__ int h_addr(int n, int h) {              // bf16 [64][256] over TB+VT
    return TB_OFF + ((n * 512 + h * 2) ^ ((n & 15) << 4));
}
__device__ __forceinline__ int ps_addr(int n, int a) {             // fp32 [64][36dw] over AH
    return AH_OFF + n * 144 + a * 4;
}

__device__ __forceinline__ uint16_t f2bf_rne(float x) {
    uint32_t u = __float_as_uint(x);
    u += 0x7FFFu + ((u >> 16) & 1u);
    return (uint16_t)(u >> 16);
}

// split 8 fp32 -> (hi bf16x8, lo bf16x8); hi = trunc, lo = trunc(x - hi)
__device__ __forceinline__ void split8(float4 a, float4 b, short8& hi, short8& lo) {
    float xs[8] = {a.x, a.y, a.z, a.w, b.x, b.y, b.z, b.w};
    U4 h, l;
#pragma unroll
    for (int p = 0; p < 4; ++p) {
        uint32_t b0 = __float_as_uint(xs[2 * p]);
        uint32_t b1 = __float_as_uint(xs[2 * p + 1]);
        float r0 = xs[2 * p]     - __uint_as_float(b0 & 0xFFFF0000u);
        float r1 = xs[2 * p + 1] - __uint_as_float(b1 & 0xFFFF0000u);
        h.u[p] = __builtin_amdgcn_perm(b1, b0, 0x07060302u);
        l.u[p] = __builtin_amdgcn_perm(__float_as_uint(r1), __float_as_uint(r0), 0x07060302u);
    }
    hi = h.s8; lo = l.s8;
}

// FUSED T/V projection: one kb-loop, A loaded once per kb, fed to M and V.
__device__ __forceinline__ void gemm_tv(const char* smem, const uint8_t* __restrict__ wb,
                                        int rowoff, int c, int l,
                                        f32x16& tacc, f32x16& vacc) {
    f32x16 z = {0.f,0.f,0.f,0.f, 0.f,0.f,0.f,0.f, 0.f,0.f,0.f,0.f, 0.f,0.f,0.f,0.f};
    tacc = z; vacc = z;
    const int n = rowoff + (l & 31), half = l >> 5;
#pragma unroll 1
    for (int kb = 0; kb < 8; ++kb) {
        const int d0 = kb * 16 + half * 8;
        U4 ah, al;
        ah.q = *(const uint4*)(smem + pl_addr(AH_OFF, n, d0));
        al.q = *(const uint4*)(smem + pl_addr(AL_OFF, n, d0));
        const uint8_t* p = wb + (size_t)((c * 8 + kb) * 2) * 1024 + (size_t)l * 16;
        U4 bh, bl;
        bh.q = *(const uint4*)p;                          // M hi/lo
        bl.q = *(const uint4*)(p + 1024);
        tacc = __builtin_amdgcn_mfma_f32_32x32x16_bf16(ah.s8, bh.s8, tacc, 0, 0, 0);
        tacc = __builtin_amdgcn_mfma_f32_32x32x16_bf16(al.s8, bh.s8, tacc, 0, 0, 0);
        tacc = __builtin_amdgcn_mfma_f32_32x32x16_bf16(ah.s8, bl.s8, tacc, 0, 0, 0);
        bh.q = *(const uint4*)(p + WSPROJ);               // V hi/lo
        bl.q = *(const uint4*)(p + WSPROJ + 1024);
        vacc = __builtin_amdgcn_mfma_f32_32x32x16_bf16(ah.s8, bh.s8, vacc, 0, 0, 0);
        vacc = __builtin_amdgcn_mfma_f32_32x32x16_bf16(al.s8, bh.s8, vacc, 0, 0, 0);
        vacc = __builtin_amdgcn_mfma_f32_32x32x16_bf16(ah.s8, bl.s8, vacc, 0, 0, 0);
    }
}

// FUSED MLP (both col-reps): A loaded once per kb, 2 accs.
__device__ __forceinline__ void gemm_mlp2(const char* smem, const uint8_t* __restrict__ mb,
                                          int rowoff, int c, int l,
                                          f32x16& a0, f32x16& a1) {
    f32x16 z = {0.f,0.f,0.f,0.f, 0.f,0.f,0.f,0.f, 0.f,0.f,0.f,0.f, 0.f,0.f,0.f,0.f};
    a0 = z; a1 = z;
    const int n = rowoff + (l & 31), half = l >> 5;
#pragma unroll 1
    for (int kb = 0; kb < 8; ++kb) {
        const int d0 = kb * 16 + half * 8;
        U4 ah, al;
        ah.q = *(const uint4*)(smem + pl_addr(AH_OFF, n, d0));
        al.q = *(const uint4*)(smem + pl_addr(AL_OFF, n, d0));
        const uint8_t* p0 = mb + (size_t)((c * 8 + kb) * 2) * 1024 + (size_t)l * 16;
        const uint8_t* p1 = mb + (size_t)(((c + 4) * 8 + kb) * 2) * 1024 + (size_t)l * 16;
        U4 bh, bl;
        bh.q = *(const uint4*)p0;
        bl.q = *(const uint4*)(p0 + 1024);
        a0 = __builtin_amdgcn_mfma_f32_32x32x16_bf16(ah.s8, bh.s8, a0, 0, 0, 0);
        a0 = __builtin_amdgcn_mfma_f32_32x32x16_bf16(al.s8, bh.s8, a0, 0, 0, 0);
        a0 = __builtin_amdgcn_mfma_f32_32x32x16_bf16(ah.s8, bl.s8, a0, 0, 0, 0);
        bh.q = *(const uint4*)p1;
        bl.q = *(const uint4*)(p1 + 1024);
        a1 = __builtin_amdgcn_mfma_f32_32x32x16_bf16(ah.s8, bh.s8, a1, 0, 0, 0);
        a1 = __builtin_amdgcn_mfma_f32_32x32x16_bf16(al.s8, bh.s8, a1, 0, 0, 0);
        a1 = __builtin_amdgcn_mfma_f32_32x32x16_bf16(ah.s8, bl.s8, a1, 0, 0, 0);
    }
}

// store 32x32 D-tile as 1-term RNE bf16 plane at row offset
__device__ __forceinline__ void store_plane32(char* smem, int base, int rowoff, int c, int l,
                                              const f32x16& a) {
    const int e = c * 32 + (l & 31);
    const int half = l >> 5;
#pragma unroll
    for (int r = 0; r < 16; ++r) {
        int n = rowoff + (r & 3) + 8 * (r >> 2) + 4 * half;   // verified 32x32 D mapping
        *(uint16_t*)(smem + pl_addr(base, n, e)) = f2bf_rne(a[r]);
    }
}

// store 32x32 D-tile as hi/lo trunc-split ACT planes at row offset
__device__ __forceinline__ void store_act32(char* smem, int rowoff, int c, int l, const f32x16& a) {
    const int e = c * 32 + (l & 31);
    const int half = l >> 5;
#pragma unroll
    for (int r = 0; r < 16; ++r) {
        int n = rowoff + (r & 3) + 8 * (r >> 2) + 4 * half;
        uint32_t bu = __float_as_uint(a[r]);
        float rr = a[r] - __uint_as_float(bu & 0xFFFF0000u);
        *(uint16_t*)(smem + pl_addr(AH_OFF, n, e)) = (uint16_t)(bu >> 16);
        *(uint16_t*)(smem + pl_addr(AL_OFF, n, e)) = (uint16_t)(__float_as_uint(rr) >> 16);
    }
}

// -------- stage 0: M = Wq^T * Wk (fp32) for both attn blocks --------
// M'[dp][d] = sum_e Wq[e][d] * Wk[e][dp]; then T = X*M', S = T*X^T == Q*K^T.
__global__ void prep_m(const float* __restrict__ Wq1, const float* __restrict__ Wk1,
                       const float* __restrict__ Wq2, const float* __restrict__ Wk2,
                       uint8_t* __restrict__ wsb) {
    const int bid = blockIdx.x;        // 0..255
    const int mat = bid >> 7;          // 0: M1, 1: M2
    const int dp  = bid & 127;
    const int d   = threadIdx.x;       // 128 threads
    const float* Wq = mat ? Wq2 : Wq1;
    const float* Wk = mat ? Wk2 : Wk1;
    float s = 0.f;
#pragma unroll 4
    for (int e = 0; e < 128; ++e)
        s += Wq[e * 128 + d] * Wk[e * 128 + dp];
    float* mf = (float*)(wsb + (mat ? M2F_OFF : M1F_OFF));
    mf[dp * 128 + d] = s;
}

// -------- stage 1: convert weights (M1,V1,M2,V2,Wp1,Wp2) to split-bf16 frags --------
__global__ void prepack(const float* __restrict__ Wv1, const float* __restrict__ Wv2,
                        const float* __restrict__ Wp1, const float* __restrict__ Wp2,
                        uint8_t* __restrict__ wsb) {
    const int bid = blockIdx.x;        // 0..199
    const int l = threadIdx.x;
    float4 fa = make_float4(0.f, 0.f, 0.f, 0.f), fb = fa;
    uint8_t* dst;
    if (bid < 128) {                       // 4 matrices: M1, V1, M2, V2
        int m = bid >> 5, rem = bid & 31, c = rem >> 3, kb = rem & 7;
        const float* W = (m == 0) ? (const float*)(wsb + M1F_OFF)
                       : (m == 1) ? Wv1
                       : (m == 2) ? (const float*)(wsb + M2F_OFF)
                       : Wv2;
        int e  = c * 32 + (l & 31);
        int d0 = kb * 16 + (l >> 5) * 8;
        const float* src = W + e * 128 + d0;
        fa = *(const float4*)src;
        fb = *(const float4*)(src + 4);
        dst = wsb + (size_t)m * WSPROJ + (size_t)((c * 8 + kb) * 2) * 1024 + l * 16;
    } else if (bid < 192) {                // Wp1 [256][128]
        int idx = bid - 128, c = idx >> 3, kb = idx & 7;
        int e  = c * 32 + (l & 31);
        int d0 = kb * 16 + (l >> 5) * 8;
        const float* src = Wp1 + e * 128 + d0;
        fa = *(const float4*)src;
        fb = *(const float4*)(src + 4);
        dst = wsb + WP1OFF + (size_t)((c * 8 + kb) * 2) * 1024 + l * 16;
    } else {                               // Wp2 [10][256] -> 16x16 B-frags
        int kb = bid - 192;
        int a  = l & 15;
        int h0 = kb * 32 + ((l >> 4) & 3) * 8;
        if (a < 10) {
            const float* src = Wp2 + a * 256 + h0;
            fa = *(const float4*)src;
            fb = *(const float4*)(src + 4);
        }
        dst = wsb + WP2OFF + (size_t)(kb * 2) * 1024 + l * 16;
    }
    short8 hi, lo;
    split8(fa, fb, hi, lo);
    *(short8*)dst = hi;
    *(short8*)(dst + 1024) = lo;
}

// -------- main fused kernel: TWO batches per block, 8 waves, 2 blocks/CU --------
// QK^T folded: S = (X*M)*X^T with M=Wq^T*Wk precomputed. Removes K-proj GEMM,
// K-plane traffic, and 2 barriers/blk (S now has a dedicated buffer). MFMA/wave
// 200 -> 152. Nothing held across barriers; spill tripwire = WRITE_SIZE >> 76MB.
__global__ __launch_bounds__(512, 4)
void fused_net(const float* __restrict__ states, const uint8_t* __restrict__ wsb,
               float* __restrict__ out_policy, float* __restrict__ out_w1,
               float* __restrict__ out_w2) {
    __shared__ __align__(16) char smem[74752];

    const int b2   = blockIdx.x;       // batch pair index
    const int t    = threadIdx.x;
    const int w    = t >> 6;           // 0..7
    const int l    = t & 63;
    const int l31  = l & 31;
    const int half = l >> 5;
    const int l15  = l & 15;
    const int g4   = (l >> 4) & 3;
    const int rh   = w >> 2;           // row-half 0/1
    const int c4   = w & 3;            // col-tile 0..3

    // ---- stage 2 batches of X into hi/lo planes, coalesced ----
    {
        const float* src = states + (size_t)b2 * 8192;
#pragma unroll
        for (int r = 0; r < 4; ++r) {
            int flat = (t + 512 * r) * 4;
            int n = flat >> 7, d0 = flat & 127;    // n 0..63
            float4 v = *(const float4*)(src + flat);
            uint32_t b0 = __float_as_uint(v.x), b1 = __float_as_uint(v.y);
            uint32_t b2u = __float_as_uint(v.z), b3 = __float_as_uint(v.w);
            float r0 = v.x - __uint_as_float(b0 & 0xFFFF0000u);
            float r1 = v.y - __uint_as_float(b1 & 0xFFFF0000u);
            float r2 = v.z - __uint_as_float(b2u & 0xFFFF0000u);
            float r3 = v.w - __uint_as_float(b3 & 0xFFFF0000u);
            uint2 hw, lw;
            hw.x = __builtin_amdgcn_perm(b1, b0, 0x07060302u);
            hw.y = __builtin_amdgcn_perm(b3, b2u, 0x07060302u);
            lw.x = __builtin_amdgcn_perm(__float_as_uint(r1), __float_as_uint(r0), 0x07060302u);
            lw.y = __builtin_amdgcn_perm(__float_as_uint(r3), __float_as_uint(r2), 0x07060302u);
            *(uint2*)(smem + pl_addr(AH_OFF, n, d0)) = hw;
            *(uint2*)(smem + pl_addr(AL_OFF, n, d0)) = lw;
        }
    }
    __syncthreads();

#pragma unroll 1
    for (int blk = 0; blk < 2; ++blk) {
        const uint8_t* wb = wsb + (size_t)(blk * 2) * WSPROJ;   // [M, V] pair

        // ---- FUSED T/V projection: A read once; both stored immediately ----
        {
            f32x16 tacc, vacc;
            gemm_tv(smem, wb, rh * 32, c4, l, tacc, vacc);
            store_plane32(smem, TB_OFF, rh * 32, c4, l, tacc);  // T 1-term RNE
            const int e = c4 * 32 + l31;
#pragma unroll
            for (int g = 0; g < 4; ++g) {                       // V merged b64 stores
                int m0 = rh * 32 + 8 * g + 4 * half;
                uint2 pk;
                pk.x = (uint32_t)f2bf_rne(vacc[4 * g])     | ((uint32_t)f2bf_rne(vacc[4 * g + 1]) << 16);
                pk.y = (uint32_t)f2bf_rne(vacc[4 * g + 2]) | ((uint32_t)f2bf_rne(vacc[4 * g + 3]) << 16);
                *(uint2*)(smem + vt_addr(e, m0)) = pk;
            }
        }
        __builtin_amdgcn_sched_barrier(0);
        __syncthreads();                        // T/V visible; X reads done

        // ---- S = (T X^T)*inv_scale: A=T (1-term), B=X (hi+lo, exact) ----
        {
            const int bq = w >> 2, rb = (w >> 1) & 1, mb = w & 1;
            const int trow = bq * 32 + rb * 16 + l15;
            const int xrow = bq * 32 + mb * 16 + l15;
            f32x4 s4 = {0.f, 0.f, 0.f, 0.f};
#pragma unroll
            for (int kb = 0; kb < 4; ++kb) {
                int e0 = kb * 32 + g4 * 8;
                U4 th, xh, xl;
                th.q = *(const uint4*)(smem + pl_addr(TB_OFF, trow, e0));
                xh.q = *(const uint4*)(smem + pl_addr(AH_OFF, xrow, e0));
                xl.q = *(const uint4*)(smem + pl_addr(AL_OFF, xrow, e0));
                s4 = __builtin_amdgcn_mfma_f32_16x16x32_bf16(th.s8, xh.s8, s4, 0, 0, 0);
                s4 = __builtin_amdgcn_mfma_f32_16x16x32_bf16(th.s8, xl.s8, s4, 0, 0, 0);
            }
            // S buffer is dedicated -> write directly, no alias barrier
#pragma unroll
            for (int r = 0; r < 4; ++r) {
                int n = bq * 32 + rb * 16 + g4 * 4 + r;    // verified 16x16 D mapping
                *(float*)(smem + s_addr(n, mb * 16 + l15)) = s4[r] * INV_SCALE;
            }
        }
        __syncthreads();

        // ---- softmax over m: 128 row-halves on waves 0-1 ----
        if (t < 128) {
            const int n = w * 32 + l31;            // w in {0,1} here
            float4 v0 = *(const float4*)(smem + s_addr(n, half * 16));
            float4 v1 = *(const float4*)(smem + s_addr(n, half * 16 + 4));
            float4 v2 = *(const float4*)(smem + s_addr(n, half * 16 + 8));
            float4 v3 = *(const float4*)(smem + s_addr(n, half * 16 + 12));
            float vv[16] = {v0.x, v0.y, v0.z, v0.w, v1.x, v1.y, v1.z, v1.w,
                            v2.x, v2.y, v2.z, v2.w, v3.x, v3.y, v3.z, v3.w};
            float mx = vv[0];
#pragma unroll
            for (int i = 1; i < 16; ++i) mx = fmaxf(mx, vv[i]);
            mx = fmaxf(mx, __shfl_xor(mx, 32));
            float sum = 0.f;
#pragma unroll
            for (int i = 0; i < 16; ++i) { vv[i] = __expf(vv[i] - mx); sum += vv[i]; }
            sum += __shfl_xor(sum, 32);
            float inv = 1.0f / sum;
#pragma unroll
            for (int i = 0; i < 16; ++i) vv[i] *= inv;
            *(float4*)(smem + s_addr(n, half * 16))      = make_float4(vv[0], vv[1], vv[2], vv[3]);
            *(float4*)(smem + s_addr(n, half * 16 + 4))  = make_float4(vv[4], vv[5], vv[6], vv[7]);
            *(float4*)(smem + s_addr(n, half * 16 + 8))  = make_float4(vv[8], vv[9], vv[10], vv[11]);
            *(float4*)(smem + s_addr(n, half * 16 + 12)) = make_float4(vv[12], vv[13], vv[14], vv[15]);
        }
        __syncthreads();

        // ---- attention-weight output for both batches (coalesced) ----
        {
            float* outw = blk ? out_w2 : out_w1;
            int f = t * 4;                          // 0..2047
            int n = f >> 5, m0 = f & 31;
            float4 o = *(const float4*)(smem + s_addr(n, m0));
            *(float4*)(outw + (size_t)b2 * 2048 + f) = o;
        }

        // ---- PV: 8 tiles (bq, c4): ACT'[n][e] = sum_m P[n][m] V[m][e] ----
        {
            const int bq = w >> 2;
            f32x16 pv = {0.f,0.f,0.f,0.f, 0.f,0.f,0.f,0.f, 0.f,0.f,0.f,0.f, 0.f,0.f,0.f,0.f};
            const int e = c4 * 32 + l31;
#pragma unroll
            for (int kb = 0; kb < 2; ++kb) {
                int m0 = kb * 16 + half * 8;
                float4 fa = *(const float4*)(smem + s_addr(bq * 32 + l31, m0));
                float4 fb = *(const float4*)(smem + s_addr(bq * 32 + l31, m0 + 4));
                short8 wh, wl;
                split8(fa, fb, wh, wl);
                U4 vh;
                vh.q = *(const uint4*)(smem + vt_addr(e, bq * 32 + m0));
                pv = __builtin_amdgcn_mfma_f32_32x32x16_bf16(wh, vh.s8, pv, 0, 0, 0);
                pv = __builtin_amdgcn_mfma_f32_32x32x16_bf16(wl, vh.s8, pv, 0, 0, 0);
            }
            store_act32(smem, bq * 32, c4, l, pv);
        }
        __builtin_amdgcn_sched_barrier(0);
        __syncthreads();
    }

    // ---- MLP hidden (fused 2 reps); H -> bf16 over dead TB+VT ----
    {
        f32x16 h0_, h1_;
        gemm_mlp2(smem, wsb + WP1OFF, rh * 32, c4, l, h0_, h1_);
#pragma unroll
        for (int rep = 0; rep < 2; ++rep) {
            const int hc = c4 + rep * 4;
            const int hcol = hc * 32 + l31;
#pragma unroll
            for (int r = 0; r < 16; ++r) {
                int n = rh * 32 + (r & 3) + 8 * (r >> 2) + 4 * half;
                float x = rep ? h1_[r] : h0_[r];
                x = fmaxf(x, 0.01f * x);            // leaky_relu
                *(uint16_t*)(smem + h_addr(n, hcol)) = f2bf_rne(x);
            }
        }
    }
    __syncthreads();

    // ---- policy logits: 4x 16x16 tiles (waves 0-3), K=256; logits -> dead AH ----
    if (w < 4) {
        f32x4 acc = {0.f, 0.f, 0.f, 0.f};
        const int n = w * 16 + l15;                 // rows 0..63
#pragma unroll
        for (int kb = 0; kb < 8; ++kb) {
            int h0 = kb * 32 + g4 * 8;
            U4 a;
            a.q = *(const uint4*)(smem + h_addr(n, h0));
            const uint8_t* p = wsb + WP2OFF + (size_t)(kb * 2) * 1024 + (size_t)l * 16;
            U4 bh, bl;
            bh.q = *(const uint4*)p;
            bl.q = *(const uint4*)(p + 1024);
            acc = __builtin_amdgcn_mfma_f32_16x16x32_bf16(a.s8, bh.s8, acc, 0, 0, 0);
            acc = __builtin_amdgcn_mfma_f32_16x16x32_bf16(a.s8, bl.s8, acc, 0, 0, 0);
        }
#pragma unroll
        for (int r = 0; r < 4; ++r) {
            int nn = w * 16 + g4 * 4 + r;
            *(float*)(smem + ps_addr(nn, l15)) = acc[r];
        }
    }
    __syncthreads();

    // ---- policy softmax over 10 actions (64 rows, wave 0) ----
    if (t < 64) {
        float v[10];
#pragma unroll
        for (int a2 = 0; a2 < 10; ++a2) v[a2] = *(const float*)(smem + ps_addr(t, a2));
        float mx = v[0];
#pragma unroll
        for (int a2 = 1; a2 < 10; ++a2) mx = fmaxf(mx, v[a2]);
        float sum = 0.f;
#pragma unroll
        for (int a2 = 0; a2 < 10; ++a2) { v[a2] = __expf(v[a2] - mx); sum += v[a2]; }
        float inv = 1.0f / sum;
#pragma unroll
        for (int a2 = 0; a2 < 10; ++a2) *(float*)(smem + ps_addr(t, a2)) = v[a2] * inv;
    }
    __syncthreads();

    for (int o = t; o < 640; o += 512) {
        int n = o / 10, a2 = o - n * 10;
        out_policy[(size_t)b2 * 640 + o] = *(const float*)(smem + ps_addr(n, a2));
    }
}

}  // namespace

extern "C" void kernel_launch(void* const* d_in, const int* in_sizes, int n_in,
                              void* d_out, int out_size, void* d_ws, size_t ws_size,
                              hipStream_t stream) {
    const float* states = (const float*)d_in[0];
    const float* Wk1 = (const float*)d_in[1];
    const float* Wq1 = (const float*)d_in[2];
    const float* Wv1 = (const float*)d_in[3];
    const float* Wk2 = (const float*)d_in[4];
    const float* Wq2 = (const float*)d_in[5];
    const float* Wv2 = (const float*)d_in[6];
    const float* Wp1 = (const float*)d_in[7];
    const float* Wp2 = (const float*)d_in[8];

    const int B = in_sizes[0] / 4096;   // 8192 batches

    uint8_t* wsb = (uint8_t*)d_ws;      // needs ~541 KB
    float* out        = (float*)d_out;
    float* out_policy = out;
    float* out_w1     = out_policy + (size_t)B * 320;
    float* out_w2     = out_w1 + (size_t)B * 1024;

    hipLaunchKernelGGL(prep_m, dim3(256), dim3(128), 0, stream,
                       Wq1, Wk1, Wq2, Wk2, wsb);
    hipLaunchKernelGGL(prepack, dim3(200), dim3(64), 0, stream,
                       Wv1, Wv2, Wp1, Wp2, wsb);
    hipLaunchKernelGGL(fused_net, dim3(B / 2), dim3(512), 0, stream,
                       states, wsb, out_policy, out_w1, out_w2);
}

// Round 16
// 171.355 us; speedup vs baseline: 1.9502x; 1.2877x over previous
//
#include <hip/hip_runtime.h>
#include <stdint.h>

namespace {

typedef __attribute__((ext_vector_type(8)))  short short8;   // 8 bf16
typedef __attribute__((ext_vector_type(16))) float f32x16;
typedef __attribute__((ext_vector_type(4)))  float f32x4;

union U4 {
    uint4    q;
    uint32_t u[4];
    uint16_t us[8];
    short8   s8;
};

constexpr float INV_SCALE = 0.08838834764831845f;  // 1/sqrt(128), BOTH attn blocks

// ---- workspace layout, bytes ----
// Weight B-matrices stored as SINGLE RNE bf16 plane (2-term GEMM: A hi/lo exact
// x B rne). Slots: [M1, V1, M2, V2], Wp1, Wp2(hi/lo), fp32 M scratch.
constexpr size_t WSPROJ  = 32768;             // 4c*8kb*1024 (single plane)
constexpr size_t WP1OFF  = 4 * WSPROJ;        // 131072 (size 65536)
constexpr size_t WP2OFF  = WP1OFF + 65536;    // 196608 (16384, hi/lo pair)
constexpr size_t M1F_OFF = WP2OFF + 16384;    // 212992 (fp32 128x128)
constexpr size_t M2F_OFF = M1F_OFF + 65536;   // 278528; end 344064

// ---- LDS arena: 74752 B (2 blocks/CU) ----
constexpr int AH_OFF = 0;       // X/WAV/NF hi plane bf16 [64][128], swizzled, 16KB
constexpr int AL_OFF = 16384;   // X/WAV/NF lo plane, 16KB
constexpr int TB_OFF = 32768;   // T = X*M, 1-term RNE plane [64][128], 16KB
constexpr int VT_OFF = 49152;   // V 1-term RNE plane [128 e][64 m] bf16, 16KB
constexpr int S_OFF  = 65536;   // DEDICATED S fp32 [64][36dw], 9216B
// H bf16 [64][256] (32KB) aliases TB+VT at MLP time; policy logits alias AH.

__device__ __forceinline__ int pl_addr(int base, int n, int e) {   // bf16 plane [64][128]
    return base + ((n * 256 + e * 2) ^ ((n & 15) << 4));
}
__device__ __forceinline__ int vt_addr(int e, int m) {             // bf16 [128][64]
    return VT_OFF + ((e * 128 + m * 2) ^ ((e & 7) << 4));
}
__device__ __forceinline__ int s_addr(int n, int m) {              // fp32 [64][36dw]
    return S_OFF + n * 144 + m * 4;
}
__device__ __forceinline__ int h_addr(int n, int h) {              // bf16 [64][256] over TB+VT
    return TB_OFF + ((n * 512 + h * 2) ^ ((n & 15) << 4));
}
__device__ __forceinline__ int ps_addr(int n, int a) {             // fp32 [64][36dw] over AH
    return AH_OFF + n * 144 + a * 4;
}

__device__ __forceinline__ uint16_t f2bf_rne(float x) {
    uint32_t u = __float_as_uint(x);
    u += 0x7FFFu + ((u >> 16) & 1u);
    return (uint16_t)(u >> 16);
}

// split 8 fp32 -> (hi bf16x8, lo bf16x8); hi = trunc, lo = trunc(x - hi)
__device__ __forceinline__ void split8(float4 a, float4 b, short8& hi, short8& lo) {
    float xs[8] = {a.x, a.y, a.z, a.w, b.x, b.y, b.z, b.w};
    U4 h, l;
#pragma unroll
    for (int p = 0; p < 4; ++p) {
        uint32_t b0 = __float_as_uint(xs[2 * p]);
        uint32_t b1 = __float_as_uint(xs[2 * p + 1]);
        float r0 = xs[2 * p]     - __uint_as_float(b0 & 0xFFFF0000u);
        float r1 = xs[2 * p + 1] - __uint_as_float(b1 & 0xFFFF0000u);
        h.u[p] = __builtin_amdgcn_perm(b1, b0, 0x07060302u);
        l.u[p] = __builtin_amdgcn_perm(__float_as_uint(r1), __float_as_uint(r0), 0x07060302u);
    }
    hi = h.s8; lo = l.s8;
}

// FUSED T/V projection: A (hi/lo exact) x B (single rne plane): 4 MFMA/kb.
__device__ __forceinline__ void gemm_tv(const char* smem, const uint8_t* __restrict__ wb,
                                        int rowoff, int c, int l,
                                        f32x16& tacc, f32x16& vacc) {
    f32x16 z = {0.f,0.f,0.f,0.f, 0.f,0.f,0.f,0.f, 0.f,0.f,0.f,0.f, 0.f,0.f,0.f,0.f};
    tacc = z; vacc = z;
    const int n = rowoff + (l & 31), half = l >> 5;
#pragma unroll 1
    for (int kb = 0; kb < 8; ++kb) {
        const int d0 = kb * 16 + half * 8;
        U4 ah, al;
        ah.q = *(const uint4*)(smem + pl_addr(AH_OFF, n, d0));
        al.q = *(const uint4*)(smem + pl_addr(AL_OFF, n, d0));
        const uint8_t* p = wb + (size_t)(c * 8 + kb) * 1024 + (size_t)l * 16;
        U4 bm, bv;
        bm.q = *(const uint4*)p;                          // M rne
        tacc = __builtin_amdgcn_mfma_f32_32x32x16_bf16(ah.s8, bm.s8, tacc, 0, 0, 0);
        tacc = __builtin_amdgcn_mfma_f32_32x32x16_bf16(al.s8, bm.s8, tacc, 0, 0, 0);
        bv.q = *(const uint4*)(p + WSPROJ);               // V rne
        vacc = __builtin_amdgcn_mfma_f32_32x32x16_bf16(ah.s8, bv.s8, vacc, 0, 0, 0);
        vacc = __builtin_amdgcn_mfma_f32_32x32x16_bf16(al.s8, bv.s8, vacc, 0, 0, 0);
    }
}

// FUSED MLP (both col-reps): A (hi/lo exact) x Wp1 (rne plane): 4 MFMA/kb.
__device__ __forceinline__ void gemm_mlp2(const char* smem, const uint8_t* __restrict__ mb,
                                          int rowoff, int c, int l,
                                          f32x16& a0, f32x16& a1) {
    f32x16 z = {0.f,0.f,0.f,0.f, 0.f,0.f,0.f,0.f, 0.f,0.f,0.f,0.f, 0.f,0.f,0.f,0.f};
    a0 = z; a1 = z;
    const int n = rowoff + (l & 31), half = l >> 5;
#pragma unroll 1
    for (int kb = 0; kb < 8; ++kb) {
        const int d0 = kb * 16 + half * 8;
        U4 ah, al;
        ah.q = *(const uint4*)(smem + pl_addr(AH_OFF, n, d0));
        al.q = *(const uint4*)(smem + pl_addr(AL_OFF, n, d0));
        const uint8_t* p0 = mb + (size_t)((c)     * 8 + kb) * 1024 + (size_t)l * 16;
        const uint8_t* p1 = mb + (size_t)((c + 4) * 8 + kb) * 1024 + (size_t)l * 16;
        U4 b0, b1;
        b0.q = *(const uint4*)p0;
        a0 = __builtin_amdgcn_mfma_f32_32x32x16_bf16(ah.s8, b0.s8, a0, 0, 0, 0);
        a0 = __builtin_amdgcn_mfma_f32_32x32x16_bf16(al.s8, b0.s8, a0, 0, 0, 0);
        b1.q = *(const uint4*)p1;
        a1 = __builtin_amdgcn_mfma_f32_32x32x16_bf16(ah.s8, b1.s8, a1, 0, 0, 0);
        a1 = __builtin_amdgcn_mfma_f32_32x32x16_bf16(al.s8, b1.s8, a1, 0, 0, 0);
    }
}

// store 32x32 D-tile as 1-term RNE bf16 plane at row offset
__device__ __forceinline__ void store_plane32(char* smem, int base, int rowoff, int c, int l,
                                              const f32x16& a) {
    const int e = c * 32 + (l & 31);
    const int half = l >> 5;
#pragma unroll
    for (int r = 0; r < 16; ++r) {
        int n = rowoff + (r & 3) + 8 * (r >> 2) + 4 * half;   // verified 32x32 D mapping
        *(uint16_t*)(smem + pl_addr(base, n, e)) = f2bf_rne(a[r]);
    }
}

// store 32x32 D-tile as hi/lo trunc-split ACT planes at row offset
__device__ __forceinline__ void store_act32(char* smem, int rowoff, int c, int l, const f32x16& a) {
    const int e = c * 32 + (l & 31);
    const int half = l >> 5;
#pragma unroll
    for (int r = 0; r < 16; ++r) {
        int n = rowoff + (r & 3) + 8 * (r >> 2) + 4 * half;
        uint32_t bu = __float_as_uint(a[r]);
        float rr = a[r] - __uint_as_float(bu & 0xFFFF0000u);
        *(uint16_t*)(smem + pl_addr(AH_OFF, n, e)) = (uint16_t)(bu >> 16);
        *(uint16_t*)(smem + pl_addr(AL_OFF, n, e)) = (uint16_t)(__float_as_uint(rr) >> 16);
    }
}

// -------- stage 0: M = Wq^T * Wk (fp32) for both attn blocks --------
__global__ void prep_m(const float* __restrict__ Wq1, const float* __restrict__ Wk1,
                       const float* __restrict__ Wq2, const float* __restrict__ Wk2,
                       uint8_t* __restrict__ wsb) {
    const int bid = blockIdx.x;        // 0..255
    const int mat = bid >> 7;          // 0: M1, 1: M2
    const int dp  = bid & 127;
    const int d   = threadIdx.x;       // 128 threads
    const float* Wq = mat ? Wq2 : Wq1;
    const float* Wk = mat ? Wk2 : Wk1;
    float s = 0.f;
#pragma unroll 4
    for (int e = 0; e < 128; ++e)
        s += Wq[e * 128 + d] * Wk[e * 128 + dp];
    float* mf = (float*)(wsb + (mat ? M2F_OFF : M1F_OFF));
    mf[dp * 128 + d] = s;
}

// -------- stage 1: pack weights. M1,V1,M2,V2,Wp1 -> single RNE plane;
//          Wp2 -> hi/lo split pair (tiny, kept 2-term). --------
__global__ void prepack(const float* __restrict__ Wv1, const float* __restrict__ Wv2,
                        const float* __restrict__ Wp1, const float* __restrict__ Wp2,
                        uint8_t* __restrict__ wsb) {
    const int bid = blockIdx.x;        // 0..199
    const int l = threadIdx.x;
    float4 fa = make_float4(0.f, 0.f, 0.f, 0.f), fb = fa;
    uint8_t* dst;
    bool rne1 = true;
    if (bid < 128) {                       // 4 matrices: M1, V1, M2, V2
        int m = bid >> 5, rem = bid & 31, c = rem >> 3, kb = rem & 7;
        const float* W = (m == 0) ? (const float*)(wsb + M1F_OFF)
                       : (m == 1) ? Wv1
                       : (m == 2) ? (const float*)(wsb + M2F_OFF)
                       : Wv2;
        int e  = c * 32 + (l & 31);
        int d0 = kb * 16 + (l >> 5) * 8;
        const float* src = W + e * 128 + d0;
        fa = *(const float4*)src;
        fb = *(const float4*)(src + 4);
        dst = wsb + (size_t)m * WSPROJ + (size_t)(c * 8 + kb) * 1024 + l * 16;
    } else if (bid < 192) {                // Wp1 [256][128]
        int idx = bid - 128, c = idx >> 3, kb = idx & 7;
        int e  = c * 32 + (l & 31);
        int d0 = kb * 16 + (l >> 5) * 8;
        const float* src = Wp1 + e * 128 + d0;
        fa = *(const float4*)src;
        fb = *(const float4*)(src + 4);
        dst = wsb + WP1OFF + (size_t)(c * 8 + kb) * 1024 + l * 16;
    } else {                               // Wp2 [10][256] -> 16x16 B-frags, hi/lo
        int kb = bid - 192;
        int a  = l & 15;
        int h0 = kb * 32 + ((l >> 4) & 3) * 8;
        if (a < 10) {
            const float* src = Wp2 + a * 256 + h0;
            fa = *(const float4*)src;
            fb = *(const float4*)(src + 4);
        }
        dst = wsb + WP2OFF + (size_t)(kb * 2) * 1024 + l * 16;
        rne1 = false;
    }
    if (rne1) {
        float xs[8] = {fa.x, fa.y, fa.z, fa.w, fb.x, fb.y, fb.z, fb.w};
        U4 hv;
#pragma unroll
        for (int i = 0; i < 8; ++i) hv.us[i] = f2bf_rne(xs[i]);
        *(short8*)dst = hv.s8;
    } else {
        short8 hi, lo;
        split8(fa, fb, hi, lo);
        *(short8*)dst = hi;
        *(short8*)(dst + 1024) = lo;
    }
}

// -------- main fused kernel: TWO batches per block, 8 waves, 2 blocks/CU --------
// 2-term GEMMs (A exact hi/lo x B single-RNE): 32x32 MFMA/wave 152 -> 104.
// Nothing held across barriers; spill tripwire = WRITE_SIZE >> 76MB.
__global__ __launch_bounds__(512, 4)
void fused_net(const float* __restrict__ states, const uint8_t* __restrict__ wsb,
               float* __restrict__ out_policy, float* __restrict__ out_w1,
               float* __restrict__ out_w2) {
    __shared__ __align__(16) char smem[74752];

    const int b2   = blockIdx.x;       // batch pair index
    const int t    = threadIdx.x;
    const int w    = t >> 6;           // 0..7
    const int l    = t & 63;
    const int l31  = l & 31;
    const int half = l >> 5;
    const int l15  = l & 15;
    const int g4   = (l >> 4) & 3;
    const int rh   = w >> 2;           // row-half 0/1
    const int c4   = w & 3;            // col-tile 0..3

    // ---- stage 2 batches of X into hi/lo planes, coalesced ----
    {
        const float* src = states + (size_t)b2 * 8192;
#pragma unroll
        for (int r = 0; r < 4; ++r) {
            int flat = (t + 512 * r) * 4;
            int n = flat >> 7, d0 = flat & 127;    // n 0..63
            float4 v = *(const float4*)(src + flat);
            uint32_t b0 = __float_as_uint(v.x), b1 = __float_as_uint(v.y);
            uint32_t b2u = __float_as_uint(v.z), b3 = __float_as_uint(v.w);
            float r0 = v.x - __uint_as_float(b0 & 0xFFFF0000u);
            float r1 = v.y - __uint_as_float(b1 & 0xFFFF0000u);
            float r2 = v.z - __uint_as_float(b2u & 0xFFFF0000u);
            float r3 = v.w - __uint_as_float(b3 & 0xFFFF0000u);
            uint2 hw, lw;
            hw.x = __builtin_amdgcn_perm(b1, b0, 0x07060302u);
            hw.y = __builtin_amdgcn_perm(b3, b2u, 0x07060302u);
            lw.x = __builtin_amdgcn_perm(__float_as_uint(r1), __float_as_uint(r0), 0x07060302u);
            lw.y = __builtin_amdgcn_perm(__float_as_uint(r3), __float_as_uint(r2), 0x07060302u);
            *(uint2*)(smem + pl_addr(AH_OFF, n, d0)) = hw;
            *(uint2*)(smem + pl_addr(AL_OFF, n, d0)) = lw;
        }
    }
    __syncthreads();

#pragma unroll 1
    for (int blk = 0; blk < 2; ++blk) {
        const uint8_t* wb = wsb + (size_t)(blk * 2) * WSPROJ;   // [M, V] pair

        // ---- FUSED T/V projection: A read once; both stored immediately ----
        {
            f32x16 tacc, vacc;
            gemm_tv(smem, wb, rh * 32, c4, l, tacc, vacc);
            store_plane32(smem, TB_OFF, rh * 32, c4, l, tacc);  // T 1-term RNE
            const int e = c4 * 32 + l31;
#pragma unroll
            for (int g = 0; g < 4; ++g) {                       // V merged b64 stores
                int m0 = rh * 32 + 8 * g + 4 * half;
                uint2 pk;
                pk.x = (uint32_t)f2bf_rne(vacc[4 * g])     | ((uint32_t)f2bf_rne(vacc[4 * g + 1]) << 16);
                pk.y = (uint32_t)f2bf_rne(vacc[4 * g + 2]) | ((uint32_t)f2bf_rne(vacc[4 * g + 3]) << 16);
                *(uint2*)(smem + vt_addr(e, m0)) = pk;
            }
        }
        __builtin_amdgcn_sched_barrier(0);
        __syncthreads();                        // T/V visible; X reads done

        // ---- S = (T X^T)*inv_scale: A=T (1-term), B=X (hi+lo, exact) ----
        {
            const int bq = w >> 2, rb = (w >> 1) & 1, mb = w & 1;
            const int trow = bq * 32 + rb * 16 + l15;
            const int xrow = bq * 32 + mb * 16 + l15;
            f32x4 s4 = {0.f, 0.f, 0.f, 0.f};
#pragma unroll
            for (int kb = 0; kb < 4; ++kb) {
                int e0 = kb * 32 + g4 * 8;
                U4 th, xh, xl;
                th.q = *(const uint4*)(smem + pl_addr(TB_OFF, trow, e0));
                xh.q = *(const uint4*)(smem + pl_addr(AH_OFF, xrow, e0));
                xl.q = *(const uint4*)(smem + pl_addr(AL_OFF, xrow, e0));
                s4 = __builtin_amdgcn_mfma_f32_16x16x32_bf16(th.s8, xh.s8, s4, 0, 0, 0);
                s4 = __builtin_amdgcn_mfma_f32_16x16x32_bf16(th.s8, xl.s8, s4, 0, 0, 0);
            }
#pragma unroll
            for (int r = 0; r < 4; ++r) {
                int n = bq * 32 + rb * 16 + g4 * 4 + r;    // verified 16x16 D mapping
                *(float*)(smem + s_addr(n, mb * 16 + l15)) = s4[r] * INV_SCALE;
            }
        }
        __syncthreads();

        // ---- softmax over m: 128 row-halves on waves 0-1 ----
        if (t < 128) {
            const int n = w * 32 + l31;            // w in {0,1} here
            float4 v0 = *(const float4*)(smem + s_addr(n, half * 16));
            float4 v1 = *(const float4*)(smem + s_addr(n, half * 16 + 4));
            float4 v2 = *(const float4*)(smem + s_addr(n, half * 16 + 8));
            float4 v3 = *(const float4*)(smem + s_addr(n, half * 16 + 12));
            float vv[16] = {v0.x, v0.y, v0.z, v0.w, v1.x, v1.y, v1.z, v1.w,
                            v2.x, v2.y, v2.z, v2.w, v3.x, v3.y, v3.z, v3.w};
            float mx = vv[0];
#pragma unroll
            for (int i = 1; i < 16; ++i) mx = fmaxf(mx, vv[i]);
            mx = fmaxf(mx, __shfl_xor(mx, 32));
            float sum = 0.f;
#pragma unroll
            for (int i = 0; i < 16; ++i) { vv[i] = __expf(vv[i] - mx); sum += vv[i]; }
            sum += __shfl_xor(sum, 32);
            float inv = 1.0f / sum;
#pragma unroll
            for (int i = 0; i < 16; ++i) vv[i] *= inv;
            *(float4*)(smem + s_addr(n, half * 16))      = make_float4(vv[0], vv[1], vv[2], vv[3]);
            *(float4*)(smem + s_addr(n, half * 16 + 4))  = make_float4(vv[4], vv[5], vv[6], vv[7]);
            *(float4*)(smem + s_addr(n, half * 16 + 8))  = make_float4(vv[8], vv[9], vv[10], vv[11]);
            *(float4*)(smem + s_addr(n, half * 16 + 12)) = make_float4(vv[12], vv[13], vv[14], vv[15]);
        }
        __syncthreads();

        // ---- attention-weight output for both batches (coalesced) ----
        {
            float* outw = blk ? out_w2 : out_w1;
            int f = t * 4;                          // 0..2047
            int n = f >> 5, m0 = f & 31;
            float4 o = *(const float4*)(smem + s_addr(n, m0));
            *(float4*)(outw + (size_t)b2 * 2048 + f) = o;
        }

        // ---- PV: 8 tiles (bq, c4): ACT'[n][e] = sum_m P[n][m] V[m][e] ----
        {
            const int bq = w >> 2;
            f32x16 pv = {0.f,0.f,0.f,0.f, 0.f,0.f,0.f,0.f, 0.f,0.f,0.f,0.f, 0.f,0.f,0.f,0.f};
            const int e = c4 * 32 + l31;
#pragma unroll
            for (int kb = 0; kb < 2; ++kb) {
                int m0 = kb * 16 + half * 8;
                float4 fa = *(const float4*)(smem + s_addr(bq * 32 + l31, m0));
                float4 fb = *(const float4*)(smem + s_addr(bq * 32 + l31, m0 + 4));
                short8 wh, wl;
                split8(fa, fb, wh, wl);
                U4 vh;
                vh.q = *(const uint4*)(smem + vt_addr(e, bq * 32 + m0));
                pv = __builtin_amdgcn_mfma_f32_32x32x16_bf16(wh, vh.s8, pv, 0, 0, 0);
                pv = __builtin_amdgcn_mfma_f32_32x32x16_bf16(wl, vh.s8, pv, 0, 0, 0);
            }
            store_act32(smem, bq * 32, c4, l, pv);
        }
        __builtin_amdgcn_sched_barrier(0);
        __syncthreads();
    }

    // ---- MLP hidden (fused 2 reps); H -> bf16 over dead TB+VT ----
    {
        f32x16 h0_, h1_;
        gemm_mlp2(smem, wsb + WP1OFF, rh * 32, c4, l, h0_, h1_);
#pragma unroll
        for (int rep = 0; rep < 2; ++rep) {
            const int hc = c4 + rep * 4;
            const int hcol = hc * 32 + l31;
#pragma unroll
            for (int r = 0; r < 16; ++r) {
                int n = rh * 32 + (r & 3) + 8 * (r >> 2) + 4 * half;
                float x = rep ? h1_[r] : h0_[r];
                x = fmaxf(x, 0.01f * x);            // leaky_relu
                *(uint16_t*)(smem + h_addr(n, hcol)) = f2bf_rne(x);
            }
        }
    }
    __syncthreads();

    // ---- policy logits: 4x 16x16 tiles (waves 0-3), K=256; logits -> dead AH ----
    if (w < 4) {
        f32x4 acc = {0.f, 0.f, 0.f, 0.f};
        const int n = w * 16 + l15;                 // rows 0..63
#pragma unroll
        for (int kb = 0; kb < 8; ++kb) {
            int h0 = kb * 32 + g4 * 8;
            U4 a;
            a.q = *(const uint4*)(smem + h_addr(n, h0));
            const uint8_t* p = wsb + WP2OFF + (size_t)(kb * 2) * 1024 + (size_t)l * 16;
            U4 bh, bl;
            bh.q = *(const uint4*)p;
            bl.q = *(const uint4*)(p + 1024);
            acc = __builtin_amdgcn_mfma_f32_16x16x32_bf16(a.s8, bh.s8, acc, 0, 0, 0);
            acc = __builtin_amdgcn_mfma_f32_16x16x32_bf16(a.s8, bl.s8, acc, 0, 0, 0);
        }
#pragma unroll
        for (int r = 0; r < 4; ++r) {
            int nn = w * 16 + g4 * 4 + r;
            *(float*)(smem + ps_addr(nn, l15)) = acc[r];
        }
    }
    __syncthreads();

    // ---- policy softmax over 10 actions (64 rows, wave 0) ----
    if (t < 64) {
        float v[10];
#pragma unroll
        for (int a2 = 0; a2 < 10; ++a2) v[a2] = *(const float*)(smem + ps_addr(t, a2));
        float mx = v[0];
#pragma unroll
        for (int a2 = 1; a2 < 10; ++a2) mx = fmaxf(mx, v[a2]);
        float sum = 0.f;
#pragma unroll
        for (int a2 = 0; a2 < 10; ++a2) { v[a2] = __expf(v[a2] - mx); sum += v[a2]; }
        float inv = 1.0f / sum;
#pragma unroll
        for (int a2 = 0; a2 < 10; ++a2) *(float*)(smem + ps_addr(t, a2)) = v[a2] * inv;
    }
    __syncthreads();

    for (int o = t; o < 640; o += 512) {
        int n = o / 10, a2 = o - n * 10;
        out_policy[(size_t)b2 * 640 + o] = *(const float*)(smem + ps_addr(n, a2));
    }
}

}  // namespace

extern "C" void kernel_launch(void* const* d_in, const int* in_sizes, int n_in,
                              void* d_out, int out_size, void* d_ws, size_t ws_size,
                              hipStream_t stream) {
    const float* states = (const float*)d_in[0];
    const float* Wk1 = (const float*)d_in[1];
    const float* Wq1 = (const float*)d_in[2];
    const float* Wv1 = (const float*)d_in[3];
    const float* Wk2 = (const float*)d_in[4];
    const float* Wq2 = (const float*)d_in[5];
    const float* Wv2 = (const float*)d_in[6];
    const float* Wp1 = (const float*)d_in[7];
    const float* Wp2 = (const float*)d_in[8];

    const int B = in_sizes[0] / 4096;   // 8192 batches

    uint8_t* wsb = (uint8_t*)d_ws;      // needs ~344 KB
    float* out        = (float*)d_out;
    float* out_policy = out;
    float* out_w1     = out_policy + (size_t)B * 320;
    float* out_w2     = out_w1 + (size_t)B * 1024;

    hipLaunchKernelGGL(prep_m, dim3(256), dim3(128), 0, stream,
                       Wq1, Wk1, Wq2, Wk2, wsb);
    hipLaunchKernelGGL(prepack, dim3(200), dim3(64), 0, stream,
                       Wv1, Wv2, Wp1, Wp2, wsb);
    hipLaunchKernelGGL(fused_net, dim3(B / 2), dim3(512), 0, stream,
                       states, wsb, out_policy, out_w1, out_w2);
}

// Round 17
// 138.327 us; speedup vs baseline: 2.4159x; 1.2388x over previous
//
#include <hip/hip_runtime.h>
#include <stdint.h>

namespace {

typedef __attribute__((ext_vector_type(8)))  short short8;   // 8 bf16
typedef __attribute__((ext_vector_type(16))) float f32x16;
typedef __attribute__((ext_vector_type(4)))  float f32x4;

union U4 {
    uint4    q;
    uint32_t u[4];
    uint16_t us[8];
    short8   s8;
};

constexpr float INV_SCALE = 0.08838834764831845f;  // 1/sqrt(128), BOTH attn blocks

// ---- workspace layout, bytes ----
// Weights as SINGLE RNE bf16 planes (M1,V1,M2,V2,Wp1); Wp2 hi/lo pair.
constexpr size_t WSPROJ  = 32768;             // 4c*8kb*1024 (single plane)
constexpr size_t WP1OFF  = 4 * WSPROJ;        // 131072 (size 65536)
constexpr size_t WP2OFF  = WP1OFF + 65536;    // 196608 (16384, hi/lo pair)
constexpr size_t M1F_OFF = WP2OFF + 16384;    // 212992 (fp32 128x128)
constexpr size_t M2F_OFF = M1F_OFF + 65536;   // 278528; end 344064

// ---- LDS arena: 58368 B (2 blocks/CU) ----
// ACT (X/WAV/NF) is now a SINGLE RNE plane: R15/R16 showed absmax is pinned by
// activation-store rne (2^-8) regardless of weight precision -> spend the
// margin here: TV/MLP MFMA halves, staging/store VALU halves.
constexpr int AH_OFF = 0;       // ACT rne plane bf16 [64][128], swizzled, 16KB
constexpr int TB_OFF = 16384;   // T = X*M, 1-term RNE plane [64][128], 16KB
constexpr int VT_OFF = 32768;   // V 1-term RNE plane [128 e][64 m] bf16, 16KB
constexpr int S_OFF  = 49152;   // DEDICATED S fp32 [64][36dw], 9216B
// H bf16 [64][256] (32KB) aliases TB+VT at MLP time; policy logits alias AH.

__device__ __forceinline__ int pl_addr(int base, int n, int e) {   // bf16 plane [64][128]
    return base + ((n * 256 + e * 2) ^ ((n & 15) << 4));
}
__device__ __forceinline__ int vt_addr(int e, int m) {             // bf16 [128][64]
    return VT_OFF + ((e * 128 + m * 2) ^ ((e & 7) << 4));
}
__device__ __forceinline__ int s_addr(int n, int m) {              // fp32 [64][36dw]
    return S_OFF + n * 144 + m * 4;
}
__device__ __forceinline__ int h_addr(int n, int h) {              // bf16 [64][256] over TB+VT
    return TB_OFF + ((n * 512 + h * 2) ^ ((n & 15) << 4));
}
__device__ __forceinline__ int ps_addr(int n, int a) {             // fp32 [64][36dw] over AH
    return AH_OFF + n * 144 + a * 4;
}

__device__ __forceinline__ uint16_t f2bf_rne(float x) {
    uint32_t u = __float_as_uint(x);
    u += 0x7FFFu + ((u >> 16) & 1u);
    return (uint16_t)(u >> 16);
}

// pack two fp32 -> one dword of 2 RNE bf16
__device__ __forceinline__ uint32_t pack2_rne(float x0, float x1) {
    uint32_t u0 = __float_as_uint(x0); u0 += 0x7FFFu + ((u0 >> 16) & 1u);
    uint32_t u1 = __float_as_uint(x1); u1 += 0x7FFFu + ((u1 >> 16) & 1u);
    return __builtin_amdgcn_perm(u1, u0, 0x07060302u);
}

// split 8 fp32 -> (hi bf16x8, lo bf16x8); hi = trunc, lo = trunc(x - hi)
__device__ __forceinline__ void split8(float4 a, float4 b, short8& hi, short8& lo) {
    float xs[8] = {a.x, a.y, a.z, a.w, b.x, b.y, b.z, b.w};
    U4 h, l;
#pragma unroll
    for (int p = 0; p < 4; ++p) {
        uint32_t b0 = __float_as_uint(xs[2 * p]);
        uint32_t b1 = __float_as_uint(xs[2 * p + 1]);
        float r0 = xs[2 * p]     - __uint_as_float(b0 & 0xFFFF0000u);
        float r1 = xs[2 * p + 1] - __uint_as_float(b1 & 0xFFFF0000u);
        h.u[p] = __builtin_amdgcn_perm(b1, b0, 0x07060302u);
        l.u[p] = __builtin_amdgcn_perm(__float_as_uint(r1), __float_as_uint(r0), 0x07060302u);
    }
    hi = h.s8; lo = l.s8;
}

// FUSED T/V projection: A (1-term rne) x B (1-term rne): 2 MFMA/kb.
__device__ __forceinline__ void gemm_tv(const char* smem, const uint8_t* __restrict__ wb,
                                        int rowoff, int c, int l,
                                        f32x16& tacc, f32x16& vacc) {
    f32x16 z = {0.f,0.f,0.f,0.f, 0.f,0.f,0.f,0.f, 0.f,0.f,0.f,0.f, 0.f,0.f,0.f,0.f};
    tacc = z; vacc = z;
    const int n = rowoff + (l & 31), half = l >> 5;
#pragma unroll 1
    for (int kb = 0; kb < 8; ++kb) {
        const int d0 = kb * 16 + half * 8;
        U4 ah;
        ah.q = *(const uint4*)(smem + pl_addr(AH_OFF, n, d0));
        const uint8_t* p = wb + (size_t)(c * 8 + kb) * 1024 + (size_t)l * 16;
        U4 bm, bv;
        bm.q = *(const uint4*)p;                          // M rne
        tacc = __builtin_amdgcn_mfma_f32_32x32x16_bf16(ah.s8, bm.s8, tacc, 0, 0, 0);
        bv.q = *(const uint4*)(p + WSPROJ);               // V rne
        vacc = __builtin_amdgcn_mfma_f32_32x32x16_bf16(ah.s8, bv.s8, vacc, 0, 0, 0);
    }
}

// FUSED MLP (both col-reps): A (1-term rne) x Wp1 (rne plane): 2 MFMA/kb.
__device__ __forceinline__ void gemm_mlp2(const char* smem, const uint8_t* __restrict__ mb,
                                          int rowoff, int c, int l,
                                          f32x16& a0, f32x16& a1) {
    f32x16 z = {0.f,0.f,0.f,0.f, 0.f,0.f,0.f,0.f, 0.f,0.f,0.f,0.f, 0.f,0.f,0.f,0.f};
    a0 = z; a1 = z;
    const int n = rowoff + (l & 31), half = l >> 5;
#pragma unroll 1
    for (int kb = 0; kb < 8; ++kb) {
        const int d0 = kb * 16 + half * 8;
        U4 ah;
        ah.q = *(const uint4*)(smem + pl_addr(AH_OFF, n, d0));
        const uint8_t* p0 = mb + (size_t)((c)     * 8 + kb) * 1024 + (size_t)l * 16;
        const uint8_t* p1 = mb + (size_t)((c + 4) * 8 + kb) * 1024 + (size_t)l * 16;
        U4 b0, b1;
        b0.q = *(const uint4*)p0;
        a0 = __builtin_amdgcn_mfma_f32_32x32x16_bf16(ah.s8, b0.s8, a0, 0, 0, 0);
        b1.q = *(const uint4*)p1;
        a1 = __builtin_amdgcn_mfma_f32_32x32x16_bf16(ah.s8, b1.s8, a1, 0, 0, 0);
    }
}

// store 32x32 D-tile as 1-term RNE bf16 plane at row offset
__device__ __forceinline__ void store_plane32(char* smem, int base, int rowoff, int c, int l,
                                              const f32x16& a) {
    const int e = c * 32 + (l & 31);
    const int half = l >> 5;
#pragma unroll
    for (int r = 0; r < 16; ++r) {
        int n = rowoff + (r & 3) + 8 * (r >> 2) + 4 * half;   // verified 32x32 D mapping
        *(uint16_t*)(smem + pl_addr(base, n, e)) = f2bf_rne(a[r]);
    }
}

// -------- stage 0: M = Wq^T * Wk (fp32) for both attn blocks --------
__global__ void prep_m(const float* __restrict__ Wq1, const float* __restrict__ Wk1,
                       const float* __restrict__ Wq2, const float* __restrict__ Wk2,
                       uint8_t* __restrict__ wsb) {
    const int bid = blockIdx.x;        // 0..255
    const int mat = bid >> 7;          // 0: M1, 1: M2
    const int dp  = bid & 127;
    const int d   = threadIdx.x;       // 128 threads
    const float* Wq = mat ? Wq2 : Wq1;
    const float* Wk = mat ? Wk2 : Wk1;
    float s = 0.f;
#pragma unroll 4
    for (int e = 0; e < 128; ++e)
        s += Wq[e * 128 + d] * Wk[e * 128 + dp];
    float* mf = (float*)(wsb + (mat ? M2F_OFF : M1F_OFF));
    mf[dp * 128 + d] = s;
}

// -------- stage 1: pack weights. M1,V1,M2,V2,Wp1 -> single RNE plane;
//          Wp2 -> hi/lo split pair (tiny, kept 2-term). --------
__global__ void prepack(const float* __restrict__ Wv1, const float* __restrict__ Wv2,
                        const float* __restrict__ Wp1, const float* __restrict__ Wp2,
                        uint8_t* __restrict__ wsb) {
    const int bid = blockIdx.x;        // 0..199
    const int l = threadIdx.x;
    float4 fa = make_float4(0.f, 0.f, 0.f, 0.f), fb = fa;
    uint8_t* dst;
    bool rne1 = true;
    if (bid < 128) {                       // 4 matrices: M1, V1, M2, V2
        int m = bid >> 5, rem = bid & 31, c = rem >> 3, kb = rem & 7;
        const float* W = (m == 0) ? (const float*)(wsb + M1F_OFF)
                       : (m == 1) ? Wv1
                       : (m == 2) ? (const float*)(wsb + M2F_OFF)
                       : Wv2;
        int e  = c * 32 + (l & 31);
        int d0 = kb * 16 + (l >> 5) * 8;
        const float* src = W + e * 128 + d0;
        fa = *(const float4*)src;
        fb = *(const float4*)(src + 4);
        dst = wsb + (size_t)m * WSPROJ + (size_t)(c * 8 + kb) * 1024 + l * 16;
    } else if (bid < 192) {                // Wp1 [256][128]
        int idx = bid - 128, c = idx >> 3, kb = idx & 7;
        int e  = c * 32 + (l & 31);
        int d0 = kb * 16 + (l >> 5) * 8;
        const float* src = Wp1 + e * 128 + d0;
        fa = *(const float4*)src;
        fb = *(const float4*)(src + 4);
        dst = wsb + WP1OFF + (size_t)(c * 8 + kb) * 1024 + l * 16;
    } else {                               // Wp2 [10][256] -> 16x16 B-frags, hi/lo
        int kb = bid - 192;
        int a  = l & 15;
        int h0 = kb * 32 + ((l >> 4) & 3) * 8;
        if (a < 10) {
            const float* src = Wp2 + a * 256 + h0;
            fa = *(const float4*)src;
            fb = *(const float4*)(src + 4);
        }
        dst = wsb + WP2OFF + (size_t)(kb * 2) * 1024 + l * 16;
        rne1 = false;
    }
    if (rne1) {
        float xs[8] = {fa.x, fa.y, fa.z, fa.w, fb.x, fb.y, fb.z, fb.w};
        U4 hv;
#pragma unroll
        for (int i = 0; i < 8; ++i) hv.us[i] = f2bf_rne(xs[i]);
        *(short8*)dst = hv.s8;
    } else {
        short8 hi, lo;
        split8(fa, fb, hi, lo);
        *(short8*)dst = hi;
        *(short8*)(dst + 1024) = lo;
    }
}

// -------- main fused kernel: TWO batches per block, 8 waves, 2 blocks/CU --------
// 1-term activations + 1-term weights: 32x32 MFMA/wave 104 -> 56.
// Nothing held across barriers; spill tripwire = WRITE_SIZE >> 76MB.
__global__ __launch_bounds__(512, 4)
void fused_net(const float* __restrict__ states, const uint8_t* __restrict__ wsb,
               float* __restrict__ out_policy, float* __restrict__ out_w1,
               float* __restrict__ out_w2) {
    __shared__ __align__(16) char smem[58368];

    const int b2   = blockIdx.x;       // batch pair index
    const int t    = threadIdx.x;
    const int w    = t >> 6;           // 0..7
    const int l    = t & 63;
    const int l31  = l & 31;
    const int half = l >> 5;
    const int l15  = l & 15;
    const int g4   = (l >> 4) & 3;
    const int rh   = w >> 2;           // row-half 0/1
    const int c4   = w & 3;            // col-tile 0..3

    // ---- stage 2 batches of X into the single rne plane, coalesced ----
    {
        const float* src = states + (size_t)b2 * 8192;
#pragma unroll
        for (int r = 0; r < 4; ++r) {
            int flat = (t + 512 * r) * 4;
            int n = flat >> 7, d0 = flat & 127;    // n 0..63
            float4 v = *(const float4*)(src + flat);
            uint2 hw;
            hw.x = pack2_rne(v.x, v.y);
            hw.y = pack2_rne(v.z, v.w);
            *(uint2*)(smem + pl_addr(AH_OFF, n, d0)) = hw;
        }
    }
    __syncthreads();

#pragma unroll 1
    for (int blk = 0; blk < 2; ++blk) {
        const uint8_t* wb = wsb + (size_t)(blk * 2) * WSPROJ;   // [M, V] pair

        // ---- FUSED T/V projection: A read once; both stored immediately ----
        {
            f32x16 tacc, vacc;
            gemm_tv(smem, wb, rh * 32, c4, l, tacc, vacc);
            store_plane32(smem, TB_OFF, rh * 32, c4, l, tacc);  // T 1-term RNE
            const int e = c4 * 32 + l31;
#pragma unroll
            for (int g = 0; g < 4; ++g) {                       // V merged b64 stores
                int m0 = rh * 32 + 8 * g + 4 * half;
                uint2 pk;
                pk.x = pack2_rne(vacc[4 * g],     vacc[4 * g + 1]);
                pk.y = pack2_rne(vacc[4 * g + 2], vacc[4 * g + 3]);
                *(uint2*)(smem + vt_addr(e, m0)) = pk;
            }
        }
        __builtin_amdgcn_sched_barrier(0);
        __syncthreads();                        // T/V visible; X reads done

        // ---- S = (T X^T)*inv_scale: A=T (1-term), B=X (1-term) ----
        {
            const int bq = w >> 2, rb = (w >> 1) & 1, mb = w & 1;
            const int trow = bq * 32 + rb * 16 + l15;
            const int xrow = bq * 32 + mb * 16 + l15;
            f32x4 s4 = {0.f, 0.f, 0.f, 0.f};
#pragma unroll
            for (int kb = 0; kb < 4; ++kb) {
                int e0 = kb * 32 + g4 * 8;
                U4 th, xh;
                th.q = *(const uint4*)(smem + pl_addr(TB_OFF, trow, e0));
                xh.q = *(const uint4*)(smem + pl_addr(AH_OFF, xrow, e0));
                s4 = __builtin_amdgcn_mfma_f32_16x16x32_bf16(th.s8, xh.s8, s4, 0, 0, 0);
            }
#pragma unroll
            for (int r = 0; r < 4; ++r) {
                int n = bq * 32 + rb * 16 + g4 * 4 + r;    // verified 16x16 D mapping
                *(float*)(smem + s_addr(n, mb * 16 + l15)) = s4[r] * INV_SCALE;
            }
        }
        __syncthreads();

        // ---- softmax over m: 128 row-halves on waves 0-1 ----
        if (t < 128) {
            const int n = w * 32 + l31;            // w in {0,1} here
            float4 v0 = *(const float4*)(smem + s_addr(n, half * 16));
            float4 v1 = *(const float4*)(smem + s_addr(n, half * 16 + 4));
            float4 v2 = *(const float4*)(smem + s_addr(n, half * 16 + 8));
            float4 v3 = *(const float4*)(smem + s_addr(n, half * 16 + 12));
            float vv[16] = {v0.x, v0.y, v0.z, v0.w, v1.x, v1.y, v1.z, v1.w,
                            v2.x, v2.y, v2.z, v2.w, v3.x, v3.y, v3.z, v3.w};
            float mx = vv[0];
#pragma unroll
            for (int i = 1; i < 16; ++i) mx = fmaxf(mx, vv[i]);
            mx = fmaxf(mx, __shfl_xor(mx, 32));
            float sum = 0.f;
#pragma unroll
            for (int i = 0; i < 16; ++i) { vv[i] = __expf(vv[i] - mx); sum += vv[i]; }
            sum += __shfl_xor(sum, 32);
            float inv = 1.0f / sum;
#pragma unroll
            for (int i = 0; i < 16; ++i) vv[i] *= inv;
            *(float4*)(smem + s_addr(n, half * 16))      = make_float4(vv[0], vv[1], vv[2], vv[3]);
            *(float4*)(smem + s_addr(n, half * 16 + 4))  = make_float4(vv[4], vv[5], vv[6], vv[7]);
            *(float4*)(smem + s_addr(n, half * 16 + 8))  = make_float4(vv[8], vv[9], vv[10], vv[11]);
            *(float4*)(smem + s_addr(n, half * 16 + 12)) = make_float4(vv[12], vv[13], vv[14], vv[15]);
        }
        __syncthreads();

        // ---- attention-weight output for both batches (coalesced) ----
        {
            float* outw = blk ? out_w2 : out_w1;
            int f = t * 4;                          // 0..2047
            int n = f >> 5, m0 = f & 31;
            float4 o = *(const float4*)(smem + s_addr(n, m0));
            *(float4*)(outw + (size_t)b2 * 2048 + f) = o;
        }

        // ---- PV: 8 tiles (bq, c4): P exact hi/lo x V 1-term; store -> ACT plane ----
        {
            const int bq = w >> 2;
            f32x16 pv = {0.f,0.f,0.f,0.f, 0.f,0.f,0.f,0.f, 0.f,0.f,0.f,0.f, 0.f,0.f,0.f,0.f};
            const int e = c4 * 32 + l31;
#pragma unroll
            for (int kb = 0; kb < 2; ++kb) {
                int m0 = kb * 16 + half * 8;
                float4 fa = *(const float4*)(smem + s_addr(bq * 32 + l31, m0));
                float4 fb = *(const float4*)(smem + s_addr(bq * 32 + l31, m0 + 4));
                short8 wh, wl;
                split8(fa, fb, wh, wl);
                U4 vh;
                vh.q = *(const uint4*)(smem + vt_addr(e, bq * 32 + m0));
                pv = __builtin_amdgcn_mfma_f32_32x32x16_bf16(wh, vh.s8, pv, 0, 0, 0);
                pv = __builtin_amdgcn_mfma_f32_32x32x16_bf16(wl, vh.s8, pv, 0, 0, 0);
            }
            store_plane32(smem, AH_OFF, bq * 32, c4, l, pv);   // WAV/NF 1-term rne
        }
        __builtin_amdgcn_sched_barrier(0);
        __syncthreads();
    }

    // ---- MLP hidden (fused 2 reps); H -> bf16 over dead TB+VT ----
    {
        f32x16 h0_, h1_;
        gemm_mlp2(smem, wsb + WP1OFF, rh * 32, c4, l, h0_, h1_);
#pragma unroll
        for (int rep = 0; rep < 2; ++rep) {
            const int hc = c4 + rep * 4;
            const int hcol = hc * 32 + l31;
#pragma unroll
            for (int r = 0; r < 16; ++r) {
                int n = rh * 32 + (r & 3) + 8 * (r >> 2) + 4 * half;
                float x = rep ? h1_[r] : h0_[r];
                x = fmaxf(x, 0.01f * x);            // leaky_relu
                *(uint16_t*)(smem + h_addr(n, hcol)) = f2bf_rne(x);
            }
        }
    }
    __syncthreads();

    // ---- policy logits: 4x 16x16 tiles (waves 0-3), K=256; logits -> dead AH ----
    if (w < 4) {
        f32x4 acc = {0.f, 0.f, 0.f, 0.f};
        const int n = w * 16 + l15;                 // rows 0..63
#pragma unroll
        for (int kb = 0; kb < 8; ++kb) {
            int h0 = kb * 32 + g4 * 8;
            U4 a;
            a.q = *(const uint4*)(smem + h_addr(n, h0));
            const uint8_t* p = wsb + WP2OFF + (size_t)(kb * 2) * 1024 + (size_t)l * 16;
            U4 bh, bl;
            bh.q = *(const uint4*)p;
            bl.q = *(const uint4*)(p + 1024);
            acc = __builtin_amdgcn_mfma_f32_16x16x32_bf16(a.s8, bh.s8, acc, 0, 0, 0);
            acc = __builtin_amdgcn_mfma_f32_16x16x32_bf16(a.s8, bl.s8, acc, 0, 0, 0);
        }
#pragma unroll
        for (int r = 0; r < 4; ++r) {
            int nn = w * 16 + g4 * 4 + r;
            *(float*)(smem + ps_addr(nn, l15)) = acc[r];
        }
    }
    __syncthreads();

    // ---- policy softmax over 10 actions (64 rows, wave 0) ----
    if (t < 64) {
        float v[10];
#pragma unroll
        for (int a2 = 0; a2 < 10; ++a2) v[a2] = *(const float*)(smem + ps_addr(t, a2));
        float mx = v[0];
#pragma unroll
        for (int a2 = 1; a2 < 10; ++a2) mx = fmaxf(mx, v[a2]);
        float sum = 0.f;
#pragma unroll
        for (int a2 = 0; a2 < 10; ++a2) { v[a2] = __expf(v[a2] - mx); sum += v[a2]; }
        float inv = 1.0f / sum;
#pragma unroll
        for (int a2 = 0; a2 < 10; ++a2) *(float*)(smem + ps_addr(t, a2)) = v[a2] * inv;
    }
    __syncthreads();

    for (int o = t; o < 640; o += 512) {
        int n = o / 10, a2 = o - n * 10;
        out_policy[(size_t)b2 * 640 + o] = *(const float*)(smem + ps_addr(n, a2));
    }
}

}  // namespace

extern "C" void kernel_launch(void* const* d_in, const int* in_sizes, int n_in,
                              void* d_out, int out_size, void* d_ws, size_t ws_size,
                              hipStream_t stream) {
    const float* states = (const float*)d_in[0];
    const float* Wk1 = (const float*)d_in[1];
    const float* Wq1 = (const float*)d_in[2];
    const float* Wv1 = (const float*)d_in[3];
    const float* Wk2 = (const float*)d_in[4];
    const float* Wq2 = (const float*)d_in[5];
    const float* Wv2 = (const float*)d_in[6];
    const float* Wp1 = (const float*)d_in[7];
    const float* Wp2 = (const float*)d_in[8];

    const int B = in_sizes[0] / 4096;   // 8192 batches

    uint8_t* wsb = (uint8_t*)d_ws;      // needs ~344 KB
    float* out        = (float*)d_out;
    float* out_policy = out;
    float* out_w1     = out_policy + (size_t)B * 320;
    float* out_w2     = out_w1 + (size_t)B * 1024;

    hipLaunchKernelGGL(prep_m, dim3(256), dim3(128), 0, stream,
                       Wq1, Wk1, Wq2, Wk2, wsb);
    hipLaunchKernelGGL(prepack, dim3(200), dim3(64), 0, stream,
                       Wv1, Wv2, Wp1, Wp2, wsb);
    hipLaunchKernelGGL(fused_net, dim3(B / 2), dim3(512), 0, stream,
                       states, wsb, out_policy, out_w1, out_w2);
}

// Round 19
// 136.391 us; speedup vs baseline: 2.4502x; 1.0142x over previous
//
#include <hip/hip_runtime.h>
#include <stdint.h>

namespace {

typedef __attribute__((ext_vector_type(8)))  short short8;   // 8 bf16
typedef __attribute__((ext_vector_type(16))) float f32x16;
typedef __attribute__((ext_vector_type(4)))  float f32x4;

union U4 {
    uint4    q;
    uint32_t u[4];
    uint16_t us[8];
    short8   s8;
};

constexpr float INV_SCALE = 0.08838834764831845f;  // 1/sqrt(128); folded into M

// ---- workspace layout, bytes ----
constexpr size_t WSPROJ  = 32768;             // 4c*8kb*1024 (single rne plane)
constexpr size_t WP1OFF  = 4 * WSPROJ;        // 131072 (size 65536)
constexpr size_t WP2OFF  = WP1OFF + 65536;    // 196608 (16384, hi/lo pair)
constexpr size_t M1F_OFF = WP2OFF + 16384;    // 212992 (fp32 128x128)
constexpr size_t M2F_OFF = M1F_OFF + 65536;   // 278528; end 344064

// ---- LDS arena: 62976 B (2 blocks/CU) ----
constexpr int AH_OFF = 0;       // ACT rne plane bf16 [64][128], swizzled, 16KB
constexpr int TB_OFF = 16384;   // T = X*(M/sqrt) rne plane [64][128], 16KB
constexpr int VT_OFF = 32768;   // V rne plane [128 e][64 m] bf16, 16KB
constexpr int S_OFF  = 49152;   // S fp32 [64][36dw], 9216B
constexpr int P_OFF  = 58368;   // P rne bf16 [64][stride 72B], 4608B
// H bf16 [64][256] (32KB) aliases TB+VT at MLP time; policy logits alias AH.

__device__ __forceinline__ int pl_addr(int base, int n, int e) {   // bf16 plane [64][128]
    return base + ((n * 256 + e * 2) ^ ((n & 15) << 4));
}
__device__ __forceinline__ int vt_addr(int e, int m) {             // bf16 [128][64]
    return VT_OFF + ((e * 128 + m * 2) ^ ((e & 7) << 4));
}
__device__ __forceinline__ int s_addr(int n, int m) {              // fp32 [64][36dw]
    return S_OFF + n * 144 + m * 4;
}
__device__ __forceinline__ int p_addr(int n, int m) {              // bf16, stride 72B
    return P_OFF + n * 72 + m * 2;
}
__device__ __forceinline__ int h_addr(int n, int h) {              // bf16 [64][256] over TB+VT
    return TB_OFF + ((n * 512 + h * 2) ^ ((n & 15) << 4));
}
__device__ __forceinline__ int ps_addr(int n, int a) {             // fp32 [64][36dw] over AH
    return AH_OFF + n * 144 + a * 4;
}

__device__ __forceinline__ uint16_t f2bf_rne(float x) {  // proven integer RNE (R2..R17)
    uint32_t u = __float_as_uint(x);
    u += 0x7FFFu + ((u >> 16) & 1u);
    return (uint16_t)(u >> 16);
}

// pack two fp32 -> one dword of 2 RNE bf16 (low16 = x0) — proven in R17 staging
__device__ __forceinline__ uint32_t pack2_rne(float x0, float x1) {
    uint32_t u0 = __float_as_uint(x0); u0 += 0x7FFFu + ((u0 >> 16) & 1u);
    uint32_t u1 = __float_as_uint(x1); u1 += 0x7FFFu + ((u1 >> 16) & 1u);
    return __builtin_amdgcn_perm(u1, u0, 0x07060302u);
}

// split 8 fp32 -> (hi bf16x8, lo bf16x8); prepack Wp2 only
__device__ __forceinline__ void split8(float4 a, float4 b, short8& hi, short8& lo) {
    float xs[8] = {a.x, a.y, a.z, a.w, b.x, b.y, b.z, b.w};
    U4 h, l;
#pragma unroll
    for (int p = 0; p < 4; ++p) {
        uint32_t b0 = __float_as_uint(xs[2 * p]);
        uint32_t b1 = __float_as_uint(xs[2 * p + 1]);
        float r0 = xs[2 * p]     - __uint_as_float(b0 & 0xFFFF0000u);
        float r1 = xs[2 * p + 1] - __uint_as_float(b1 & 0xFFFF0000u);
        h.u[p] = __builtin_amdgcn_perm(b1, b0, 0x07060302u);
        l.u[p] = __builtin_amdgcn_perm(__float_as_uint(r1), __float_as_uint(r0), 0x07060302u);
    }
    hi = h.s8; lo = l.s8;
}

// FUSED T/V projection: 2 MFMA/kb (A rne x B rne)
__device__ __forceinline__ void gemm_tv(const char* smem, const uint8_t* __restrict__ wb,
                                        int rowoff, int c, int l,
                                        f32x16& tacc, f32x16& vacc) {
    f32x16 z = {0.f,0.f,0.f,0.f, 0.f,0.f,0.f,0.f, 0.f,0.f,0.f,0.f, 0.f,0.f,0.f,0.f};
    tacc = z; vacc = z;
    const int n = rowoff + (l & 31), half = l >> 5;
#pragma unroll 1
    for (int kb = 0; kb < 8; ++kb) {
        const int d0 = kb * 16 + half * 8;
        U4 ah;
        ah.q = *(const uint4*)(smem + pl_addr(AH_OFF, n, d0));
        const uint8_t* p = wb + (size_t)(c * 8 + kb) * 1024 + (size_t)l * 16;
        U4 bm, bv;
        bm.q = *(const uint4*)p;
        tacc = __builtin_amdgcn_mfma_f32_32x32x16_bf16(ah.s8, bm.s8, tacc, 0, 0, 0);
        bv.q = *(const uint4*)(p + WSPROJ);
        vacc = __builtin_amdgcn_mfma_f32_32x32x16_bf16(ah.s8, bv.s8, vacc, 0, 0, 0);
    }
}

// FUSED MLP (both col-reps): 2 MFMA/kb
__device__ __forceinline__ void gemm_mlp2(const char* smem, const uint8_t* __restrict__ mb,
                                          int rowoff, int c, int l,
                                          f32x16& a0, f32x16& a1) {
    f32x16 z = {0.f,0.f,0.f,0.f, 0.f,0.f,0.f,0.f, 0.f,0.f,0.f,0.f, 0.f,0.f,0.f,0.f};
    a0 = z; a1 = z;
    const int n = rowoff + (l & 31), half = l >> 5;
#pragma unroll 1
    for (int kb = 0; kb < 8; ++kb) {
        const int d0 = kb * 16 + half * 8;
        U4 ah;
        ah.q = *(const uint4*)(smem + pl_addr(AH_OFF, n, d0));
        const uint8_t* p0 = mb + (size_t)((c)     * 8 + kb) * 1024 + (size_t)l * 16;
        const uint8_t* p1 = mb + (size_t)((c + 4) * 8 + kb) * 1024 + (size_t)l * 16;
        U4 b0, b1;
        b0.q = *(const uint4*)p0;
        a0 = __builtin_amdgcn_mfma_f32_32x32x16_bf16(ah.s8, b0.s8, a0, 0, 0, 0);
        b1.q = *(const uint4*)p1;
        a1 = __builtin_amdgcn_mfma_f32_32x32x16_bf16(ah.s8, b1.s8, a1, 0, 0, 0);
    }
}

// store 32x32 D-tile as RNE bf16 plane (integer path, proven)
__device__ __forceinline__ void store_plane32(char* smem, int base, int rowoff, int c, int l,
                                              const f32x16& a) {
    const int e = c * 32 + (l & 31);
    const int half = l >> 5;
#pragma unroll
    for (int r = 0; r < 16; ++r) {
        int n = rowoff + (r & 3) + 8 * (r >> 2) + 4 * half;   // verified 32x32 D mapping
        *(uint16_t*)(smem + pl_addr(base, n, e)) = f2bf_rne(a[r]);
    }
}

// -------- stage 0: M = (Wq^T * Wk) * INV_SCALE (fp32) for both attn blocks --------
__global__ void prep_m(const float* __restrict__ Wq1, const float* __restrict__ Wk1,
                       const float* __restrict__ Wq2, const float* __restrict__ Wk2,
                       uint8_t* __restrict__ wsb) {
    const int bid = blockIdx.x;        // 0..255
    const int mat = bid >> 7;          // 0: M1, 1: M2
    const int dp  = bid & 127;
    const int d   = threadIdx.x;       // 128 threads
    const float* Wq = mat ? Wq2 : Wq1;
    const float* Wk = mat ? Wk2 : Wk1;
    float s = 0.f;
#pragma unroll 4
    for (int e = 0; e < 128; ++e)
        s += Wq[e * 128 + d] * Wk[e * 128 + dp];
    float* mf = (float*)(wsb + (mat ? M2F_OFF : M1F_OFF));
    mf[dp * 128 + d] = s * INV_SCALE;
}

// -------- stage 1: pack weights. M1,V1,M2,V2,Wp1 -> single RNE plane; Wp2 hi/lo --------
__global__ void prepack(const float* __restrict__ Wv1, const float* __restrict__ Wv2,
                        const float* __restrict__ Wp1, const float* __restrict__ Wp2,
                        uint8_t* __restrict__ wsb) {
    const int bid = blockIdx.x;        // 0..199
    const int l = threadIdx.x;
    float4 fa = make_float4(0.f, 0.f, 0.f, 0.f), fb = fa;
    uint8_t* dst;
    bool rne1 = true;
    if (bid < 128) {                       // 4 matrices: M1, V1, M2, V2
        int m = bid >> 5, rem = bid & 31, c = rem >> 3, kb = rem & 7;
        const float* W = (m == 0) ? (const float*)(wsb + M1F_OFF)
                       : (m == 1) ? Wv1
                       : (m == 2) ? (const float*)(wsb + M2F_OFF)
                       : Wv2;
        int e  = c * 32 + (l & 31);
        int d0 = kb * 16 + (l >> 5) * 8;
        const float* src = W + e * 128 + d0;
        fa = *(const float4*)src;
        fb = *(const float4*)(src + 4);
        dst = wsb + (size_t)m * WSPROJ + (size_t)(c * 8 + kb) * 1024 + l * 16;
    } else if (bid < 192) {                // Wp1 [256][128]
        int idx = bid - 128, c = idx >> 3, kb = idx & 7;
        int e  = c * 32 + (l & 31);
        int d0 = kb * 16 + (l >> 5) * 8;
        const float* src = Wp1 + e * 128 + d0;
        fa = *(const float4*)src;
        fb = *(const float4*)(src + 4);
        dst = wsb + WP1OFF + (size_t)(c * 8 + kb) * 1024 + l * 16;
    } else {                               // Wp2 [10][256] -> 16x16 B-frags, hi/lo
        int kb = bid - 192;
        int a  = l & 15;
        int h0 = kb * 32 + ((l >> 4) & 3) * 8;
        if (a < 10) {
            const float* src = Wp2 + a * 256 + h0;
            fa = *(const float4*)src;
            fb = *(const float4*)(src + 4);
        }
        dst = wsb + WP2OFF + (size_t)(kb * 2) * 1024 + l * 16;
        rne1 = false;
    }
    if (rne1) {
        float xs[8] = {fa.x, fa.y, fa.z, fa.w, fb.x, fb.y, fb.z, fb.w};
        U4 hv;
#pragma unroll
        for (int i = 0; i < 8; ++i) hv.us[i] = f2bf_rne(xs[i]);
        *(short8*)dst = hv.s8;
    } else {
        short8 hi, lo;
        split8(fa, fb, hi, lo);
        *(short8*)dst = hi;
        *(short8*)(dst + 1024) = lo;
    }
}

// -------- main fused kernel: TWO batches per block, 8 waves, 2 blocks/CU --------
// R18 lesson: v_cvt_pk_bf16_f32 inline-asm produced garbage (NaN cascade) — all
// packs use the proven integer RNE path. Structural wins kept: all-wave softmax
// fused with global w-write; P as rne bf16 plane -> PV 1 MFMA/kb, no split8;
// INV_SCALE folded into M. Spill tripwire = WRITE_SIZE >> 76MB.
__global__ __launch_bounds__(512, 4)
void fused_net(const float* __restrict__ states, const uint8_t* __restrict__ wsb,
               float* __restrict__ out_policy, float* __restrict__ out_w1,
               float* __restrict__ out_w2) {
    __shared__ __align__(16) char smem[62976];

    const int b2   = blockIdx.x;       // batch pair index
    const int t    = threadIdx.x;
    const int w    = t >> 6;           // 0..7
    const int l    = t & 63;
    const int l31  = l & 31;
    const int half = l >> 5;
    const int l15  = l & 15;
    const int g4   = (l >> 4) & 3;
    const int rh   = w >> 2;           // row-half 0/1
    const int c4   = w & 3;            // col-tile 0..3

    // ---- stage 2 batches of X into the rne plane, coalesced ----
    {
        const float* src = states + (size_t)b2 * 8192;
#pragma unroll
        for (int r = 0; r < 4; ++r) {
            int flat = (t + 512 * r) * 4;
            int n = flat >> 7, d0 = flat & 127;    // n 0..63
            float4 v = *(const float4*)(src + flat);
            uint2 hw;
            hw.x = pack2_rne(v.x, v.y);
            hw.y = pack2_rne(v.z, v.w);
            *(uint2*)(smem + pl_addr(AH_OFF, n, d0)) = hw;
        }
    }
    __syncthreads();

#pragma unroll 1
    for (int blk = 0; blk < 2; ++blk) {
        const uint8_t* wb = wsb + (size_t)(blk * 2) * WSPROJ;   // [M, V] pair

        // ---- FUSED T/V projection ----
        {
            f32x16 tacc, vacc;
            gemm_tv(smem, wb, rh * 32, c4, l, tacc, vacc);
            store_plane32(smem, TB_OFF, rh * 32, c4, l, tacc);
            const int e = c4 * 32 + l31;
#pragma unroll
            for (int g = 0; g < 4; ++g) {                       // V merged b64 stores
                int m0 = rh * 32 + 8 * g + 4 * half;
                uint2 pk;
                pk.x = pack2_rne(vacc[4 * g],     vacc[4 * g + 1]);
                pk.y = pack2_rne(vacc[4 * g + 2], vacc[4 * g + 3]);
                *(uint2*)(smem + vt_addr(e, m0)) = pk;
            }
        }
        __builtin_amdgcn_sched_barrier(0);
        __syncthreads();                        // T/V visible; X reads done

        // ---- S = T X^T (scale already in M): 8 16x16 tiles, one per wave ----
        {
            const int bq = w >> 2, rb = (w >> 1) & 1, mb = w & 1;
            const int trow = bq * 32 + rb * 16 + l15;
            const int xrow = bq * 32 + mb * 16 + l15;
            f32x4 s4 = {0.f, 0.f, 0.f, 0.f};
#pragma unroll
            for (int kb = 0; kb < 4; ++kb) {
                int e0 = kb * 32 + g4 * 8;
                U4 th, xh;
                th.q = *(const uint4*)(smem + pl_addr(TB_OFF, trow, e0));
                xh.q = *(const uint4*)(smem + pl_addr(AH_OFF, xrow, e0));
                s4 = __builtin_amdgcn_mfma_f32_16x16x32_bf16(th.s8, xh.s8, s4, 0, 0, 0);
            }
#pragma unroll
            for (int r = 0; r < 4; ++r) {
                int n = bq * 32 + rb * 16 + g4 * 4 + r;    // verified 16x16 D mapping
                *(float*)(smem + s_addr(n, mb * 16 + l15)) = s4[r];
            }
        }
        __syncthreads();

        // ---- softmax (ALL 512 threads): row n=t>>3, 4 cols each; 8-lane reduce;
        //      writes global weights (coalesced) + P rne plane ----
        {
            const int n  = t >> 3;
            const int mq = (t & 7) * 4;
            float4 v = *(const float4*)(smem + s_addr(n, mq));
            float mx = fmaxf(fmaxf(v.x, v.y), fmaxf(v.z, v.w));
            mx = fmaxf(mx, __shfl_xor(mx, 1));
            mx = fmaxf(mx, __shfl_xor(mx, 2));
            mx = fmaxf(mx, __shfl_xor(mx, 4));
            v.x = __expf(v.x - mx); v.y = __expf(v.y - mx);
            v.z = __expf(v.z - mx); v.w = __expf(v.w - mx);
            float s = v.x + v.y + v.z + v.w;
            s += __shfl_xor(s, 1);
            s += __shfl_xor(s, 2);
            s += __shfl_xor(s, 4);
            float inv = 1.0f / s;
            v.x *= inv; v.y *= inv; v.z *= inv; v.w *= inv;
            float* outw = blk ? out_w2 : out_w1;
            *(float4*)(outw + (size_t)b2 * 2048 + n * 32 + mq) = v;
            uint2 pb;
            pb.x = pack2_rne(v.x, v.y);
            pb.y = pack2_rne(v.z, v.w);
            *(uint2*)(smem + p_addr(n, mq)) = pb;
        }
        __syncthreads();

        // ---- PV: P (rne plane) x V (rne plane): 1 MFMA/kb; store -> ACT plane ----
        {
            const int bq = w >> 2;
            f32x16 pv = {0.f,0.f,0.f,0.f, 0.f,0.f,0.f,0.f, 0.f,0.f,0.f,0.f, 0.f,0.f,0.f,0.f};
            const int e = c4 * 32 + l31;
#pragma unroll
            for (int kb = 0; kb < 2; ++kb) {
                int m0 = kb * 16 + half * 8;
                U4 pa, vh;
                int pbase = p_addr(bq * 32 + l31, m0);
                *(uint2*)&pa.u[0] = *(const uint2*)(smem + pbase);
                *(uint2*)&pa.u[2] = *(const uint2*)(smem + pbase + 8);
                vh.q = *(const uint4*)(smem + vt_addr(e, bq * 32 + m0));
                pv = __builtin_amdgcn_mfma_f32_32x32x16_bf16(pa.s8, vh.s8, pv, 0, 0, 0);
            }
            store_plane32(smem, AH_OFF, bq * 32, c4, l, pv);   // WAV/NF rne
        }
        __builtin_amdgcn_sched_barrier(0);
        __syncthreads();
    }

    // ---- MLP hidden (fused 2 reps); H -> bf16 over dead TB+VT ----
    {
        f32x16 h0_, h1_;
        gemm_mlp2(smem, wsb + WP1OFF, rh * 32, c4, l, h0_, h1_);
#pragma unroll
        for (int rep = 0; rep < 2; ++rep) {
            const int hc = c4 + rep * 4;
            const int hcol = hc * 32 + l31;
#pragma unroll
            for (int r = 0; r < 16; ++r) {
                int n = rh * 32 + (r & 3) + 8 * (r >> 2) + 4 * half;
                float x = rep ? h1_[r] : h0_[r];
                x = fmaxf(x, 0.01f * x);            // leaky_relu
                *(uint16_t*)(smem + h_addr(n, hcol)) = f2bf_rne(x);
            }
        }
    }
    __syncthreads();

    // ---- policy logits: 4x 16x16 tiles (waves 0-3), K=256; logits -> dead AH ----
    if (w < 4) {
        f32x4 acc = {0.f, 0.f, 0.f, 0.f};
        const int n = w * 16 + l15;                 // rows 0..63
#pragma unroll
        for (int kb = 0; kb < 8; ++kb) {
            int h0 = kb * 32 + g4 * 8;
            U4 a;
            a.q = *(const uint4*)(smem + h_addr(n, h0));
            const uint8_t* p = wsb + WP2OFF + (size_t)(kb * 2) * 1024 + (size_t)l * 16;
            U4 bh, bl;
            bh.q = *(const uint4*)p;
            bl.q = *(const uint4*)(p + 1024);
            acc = __builtin_amdgcn_mfma_f32_16x16x32_bf16(a.s8, bh.s8, acc, 0, 0, 0);
            acc = __builtin_amdgcn_mfma_f32_16x16x32_bf16(a.s8, bl.s8, acc, 0, 0, 0);
        }
#pragma unroll
        for (int r = 0; r < 4; ++r) {
            int nn = w * 16 + g4 * 4 + r;
            *(float*)(smem + ps_addr(nn, l15)) = acc[r];
        }
    }
    __syncthreads();

    // ---- policy softmax over 10 actions (64 rows, wave 0) ----
    if (t < 64) {
        float v[10];
#pragma unroll
        for (int a2 = 0; a2 < 10; ++a2) v[a2] = *(const float*)(smem + ps_addr(t, a2));
        float mx = v[0];
#pragma unroll
        for (int a2 = 1; a2 < 10; ++a2) mx = fmaxf(mx, v[a2]);
        float sum = 0.f;
#pragma unroll
        for (int a2 = 0; a2 < 10; ++a2) { v[a2] = __expf(v[a2] - mx); sum += v[a2]; }
        float inv = 1.0f / sum;
#pragma unroll
        for (int a2 = 0; a2 < 10; ++a2) *(float*)(smem + ps_addr(t, a2)) = v[a2] * inv;
    }
    __syncthreads();

    for (int o = t; o < 640; o += 512) {
        int n = o / 10, a2 = o - n * 10;
        out_policy[(size_t)b2 * 640 + o] = *(const float*)(smem + ps_addr(n, a2));
    }
}

}  // namespace

extern "C" void kernel_launch(void* const* d_in, const int* in_sizes, int n_in,
                              void* d_out, int out_size, void* d_ws, size_t ws_size,
                              hipStream_t stream) {
    const float* states = (const float*)d_in[0];
    const float* Wk1 = (const float*)d_in[1];
    const float* Wq1 = (const float*)d_in[2];
    const float* Wv1 = (const float*)d_in[3];
    const float* Wk2 = (const float*)d_in[4];
    const float* Wq2 = (const float*)d_in[5];
    const float* Wv2 = (const float*)d_in[6];
    const float* Wp1 = (const float*)d_in[7];
    const float* Wp2 = (const float*)d_in[8];

    const int B = in_sizes[0] / 4096;   // 8192 batches

    uint8_t* wsb = (uint8_t*)d_ws;      // needs ~344 KB
    float* out        = (float*)d_out;
    float* out_policy = out;
    float* out_w1     = out_policy + (size_t)B * 320;
    float* out_w2     = out_w1 + (size_t)B * 1024;

    hipLaunchKernelGGL(prep_m, dim3(256), dim3(128), 0, stream,
                       Wq1, Wk1, Wq2, Wk2, wsb);
    hipLaunchKernelGGL(prepack, dim3(200), dim3(64), 0, stream,
                       Wv1, Wv2, Wp1, Wp2, wsb);
    hipLaunchKernelGGL(fused_net, dim3(B / 2), dim3(512), 0, stream,
                       states, wsb, out_policy, out_w1, out_w2);
}

// Round 20
// 136.248 us; speedup vs baseline: 2.4528x; 1.0010x over previous
//
#include <hip/hip_runtime.h>
#include <stdint.h>

namespace {

typedef __attribute__((ext_vector_type(8)))  short short8;   // 8 bf16
typedef __attribute__((ext_vector_type(16))) float f32x16;
typedef __attribute__((ext_vector_type(4)))  float f32x4;

union U4 {
    uint4    q;
    uint32_t u[4];
    uint16_t us[8];
    short8   s8;
};

constexpr float INV_SCALE = 0.08838834764831845f;  // 1/sqrt(128); folded into M

// ---- workspace layout, bytes ----
constexpr size_t WSPROJ  = 32768;             // 4c*8kb*1024 (single rne plane)
constexpr size_t WP1OFF  = 4 * WSPROJ;        // 131072 (size 65536)
constexpr size_t WP2OFF  = WP1OFF + 65536;    // 196608 (16384, hi/lo pair)
constexpr size_t M1F_OFF = WP2OFF + 16384;    // 212992 (fp32 128x128)
constexpr size_t M2F_OFF = M1F_OFF + 65536;   // 278528; end 344064

// ---- LDS arena: 53760 B -> 3 blocks/CU (161280 <= 163840) ----
// S fp32 ALIASES the TB region (T dead after S-phase reads; one extra barrier).
constexpr int AH_OFF = 0;       // ACT rne plane bf16 [64][128], swizzled, 16KB
constexpr int TB_OFF = 16384;   // T = X*(M/sqrt) rne plane [64][128], 16KB; S fp32 aliases
constexpr int VT_OFF = 32768;   // V rne plane [128 e][64 m] bf16, 16KB
constexpr int P_OFF  = 49152;   // P rne bf16 [64][stride 72B], 4608B
// H bf16 [64][256] (32KB) aliases TB+VT at MLP time; policy logits alias AH.

__device__ __forceinline__ int pl_addr(int base, int n, int e) {   // bf16 plane [64][128]
    return base + ((n * 256 + e * 2) ^ ((n & 15) << 4));
}
__device__ __forceinline__ int vt_addr(int e, int m) {             // bf16 [128][64]
    return VT_OFF + ((e * 128 + m * 2) ^ ((e & 7) << 4));
}
__device__ __forceinline__ int s_addr(int n, int m) {              // fp32 [64][36dw] over TB
    return TB_OFF + n * 144 + m * 4;
}
__device__ __forceinline__ int p_addr(int n, int m) {              // bf16, stride 72B
    return P_OFF + n * 72 + m * 2;
}
__device__ __forceinline__ int h_addr(int n, int h) {              // bf16 [64][256] over TB+VT
    return TB_OFF + ((n * 512 + h * 2) ^ ((n & 15) << 4));
}
__device__ __forceinline__ int ps_addr(int n, int a) {             // fp32 [64][36dw] over AH
    return AH_OFF + n * 144 + a * 4;
}

__device__ __forceinline__ uint16_t f2bf_rne(float x) {  // proven integer RNE (R2..R19)
    uint32_t u = __float_as_uint(x);
    u += 0x7FFFu + ((u >> 16) & 1u);
    return (uint16_t)(u >> 16);
}

// pack two fp32 -> one dword of 2 RNE bf16 (low16 = x0)
__device__ __forceinline__ uint32_t pack2_rne(float x0, float x1) {
    uint32_t u0 = __float_as_uint(x0); u0 += 0x7FFFu + ((u0 >> 16) & 1u);
    uint32_t u1 = __float_as_uint(x1); u1 += 0x7FFFu + ((u1 >> 16) & 1u);
    return __builtin_amdgcn_perm(u1, u0, 0x07060302u);
}

// split 8 fp32 -> (hi bf16x8, lo bf16x8); prepack Wp2 only
__device__ __forceinline__ void split8(float4 a, float4 b, short8& hi, short8& lo) {
    float xs[8] = {a.x, a.y, a.z, a.w, b.x, b.y, b.z, b.w};
    U4 h, l;
#pragma unroll
    for (int p = 0; p < 4; ++p) {
        uint32_t b0 = __float_as_uint(xs[2 * p]);
        uint32_t b1 = __float_as_uint(xs[2 * p + 1]);
        float r0 = xs[2 * p]     - __uint_as_float(b0 & 0xFFFF0000u);
        float r1 = xs[2 * p + 1] - __uint_as_float(b1 & 0xFFFF0000u);
        h.u[p] = __builtin_amdgcn_perm(b1, b0, 0x07060302u);
        l.u[p] = __builtin_amdgcn_perm(__float_as_uint(r1), __float_as_uint(r0), 0x07060302u);
    }
    hi = h.s8; lo = l.s8;
}

// FUSED T/V projection: 2 MFMA/kb (A rne x B rne)
__device__ __forceinline__ void gemm_tv(const char* smem, const uint8_t* __restrict__ wb,
                                        int rowoff, int c, int l,
                                        f32x16& tacc, f32x16& vacc) {
    f32x16 z = {0.f,0.f,0.f,0.f, 0.f,0.f,0.f,0.f, 0.f,0.f,0.f,0.f, 0.f,0.f,0.f,0.f};
    tacc = z; vacc = z;
    const int n = rowoff + (l & 31), half = l >> 5;
#pragma unroll 1
    for (int kb = 0; kb < 8; ++kb) {
        const int d0 = kb * 16 + half * 8;
        U4 ah;
        ah.q = *(const uint4*)(smem + pl_addr(AH_OFF, n, d0));
        const uint8_t* p = wb + (size_t)(c * 8 + kb) * 1024 + (size_t)l * 16;
        U4 bm, bv;
        bm.q = *(const uint4*)p;
        tacc = __builtin_amdgcn_mfma_f32_32x32x16_bf16(ah.s8, bm.s8, tacc, 0, 0, 0);
        bv.q = *(const uint4*)(p + WSPROJ);
        vacc = __builtin_amdgcn_mfma_f32_32x32x16_bf16(ah.s8, bv.s8, vacc, 0, 0, 0);
    }
}

// FUSED MLP (both col-reps): 2 MFMA/kb
__device__ __forceinline__ void gemm_mlp2(const char* smem, const uint8_t* __restrict__ mb,
                                          int rowoff, int c, int l,
                                          f32x16& a0, f32x16& a1) {
    f32x16 z = {0.f,0.f,0.f,0.f, 0.f,0.f,0.f,0.f, 0.f,0.f,0.f,0.f, 0.f,0.f,0.f,0.f};
    a0 = z; a1 = z;
    const int n = rowoff + (l & 31), half = l >> 5;
#pragma unroll 1
    for (int kb = 0; kb < 8; ++kb) {
        const int d0 = kb * 16 + half * 8;
        U4 ah;
        ah.q = *(const uint4*)(smem + pl_addr(AH_OFF, n, d0));
        const uint8_t* p0 = mb + (size_t)((c)     * 8 + kb) * 1024 + (size_t)l * 16;
        const uint8_t* p1 = mb + (size_t)((c + 4) * 8 + kb) * 1024 + (size_t)l * 16;
        U4 b0, b1;
        b0.q = *(const uint4*)p0;
        a0 = __builtin_amdgcn_mfma_f32_32x32x16_bf16(ah.s8, b0.s8, a0, 0, 0, 0);
        b1.q = *(const uint4*)p1;
        a1 = __builtin_amdgcn_mfma_f32_32x32x16_bf16(ah.s8, b1.s8, a1, 0, 0, 0);
    }
}

// store 32x32 D-tile as RNE bf16 plane (integer path, proven)
__device__ __forceinline__ void store_plane32(char* smem, int base, int rowoff, int c, int l,
                                              const f32x16& a) {
    const int e = c * 32 + (l & 31);
    const int half = l >> 5;
#pragma unroll
    for (int r = 0; r < 16; ++r) {
        int n = rowoff + (r & 3) + 8 * (r >> 2) + 4 * half;   // verified 32x32 D mapping
        *(uint16_t*)(smem + pl_addr(base, n, e)) = f2bf_rne(a[r]);
    }
}

// -------- stage 0: M = (Wq^T * Wk) * INV_SCALE (fp32) for both attn blocks --------
__global__ void prep_m(const float* __restrict__ Wq1, const float* __restrict__ Wk1,
                       const float* __restrict__ Wq2, const float* __restrict__ Wk2,
                       uint8_t* __restrict__ wsb) {
    const int bid = blockIdx.x;        // 0..255
    const int mat = bid >> 7;          // 0: M1, 1: M2
    const int dp  = bid & 127;
    const int d   = threadIdx.x;       // 128 threads
    const float* Wq = mat ? Wq2 : Wq1;
    const float* Wk = mat ? Wk2 : Wk1;
    float s = 0.f;
#pragma unroll 4
    for (int e = 0; e < 128; ++e)
        s += Wq[e * 128 + d] * Wk[e * 128 + dp];
    float* mf = (float*)(wsb + (mat ? M2F_OFF : M1F_OFF));
    mf[dp * 128 + d] = s * INV_SCALE;
}

// -------- stage 1: pack weights. M1,V1,M2,V2,Wp1 -> single RNE plane; Wp2 hi/lo --------
__global__ void prepack(const float* __restrict__ Wv1, const float* __restrict__ Wv2,
                        const float* __restrict__ Wp1, const float* __restrict__ Wp2,
                        uint8_t* __restrict__ wsb) {
    const int bid = blockIdx.x;        // 0..199
    const int l = threadIdx.x;
    float4 fa = make_float4(0.f, 0.f, 0.f, 0.f), fb = fa;
    uint8_t* dst;
    bool rne1 = true;
    if (bid < 128) {                       // 4 matrices: M1, V1, M2, V2
        int m = bid >> 5, rem = bid & 31, c = rem >> 3, kb = rem & 7;
        const float* W = (m == 0) ? (const float*)(wsb + M1F_OFF)
                       : (m == 1) ? Wv1
                       : (m == 2) ? (const float*)(wsb + M2F_OFF)
                       : Wv2;
        int e  = c * 32 + (l & 31);
        int d0 = kb * 16 + (l >> 5) * 8;
        const float* src = W + e * 128 + d0;
        fa = *(const float4*)src;
        fb = *(const float4*)(src + 4);
        dst = wsb + (size_t)m * WSPROJ + (size_t)(c * 8 + kb) * 1024 + l * 16;
    } else if (bid < 192) {                // Wp1 [256][128]
        int idx = bid - 128, c = idx >> 3, kb = idx & 7;
        int e  = c * 32 + (l & 31);
        int d0 = kb * 16 + (l >> 5) * 8;
        const float* src = Wp1 + e * 128 + d0;
        fa = *(const float4*)src;
        fb = *(const float4*)(src + 4);
        dst = wsb + WP1OFF + (size_t)(c * 8 + kb) * 1024 + l * 16;
    } else {                               // Wp2 [10][256] -> 16x16 B-frags, hi/lo
        int kb = bid - 192;
        int a  = l & 15;
        int h0 = kb * 32 + ((l >> 4) & 3) * 8;
        if (a < 10) {
            const float* src = Wp2 + a * 256 + h0;
            fa = *(const float4*)src;
            fb = *(const float4*)(src + 4);
        }
        dst = wsb + WP2OFF + (size_t)(kb * 2) * 1024 + l * 16;
        rne1 = false;
    }
    if (rne1) {
        float xs[8] = {fa.x, fa.y, fa.z, fa.w, fb.x, fb.y, fb.z, fb.w};
        U4 hv;
#pragma unroll
        for (int i = 0; i < 8; ++i) hv.us[i] = f2bf_rne(xs[i]);
        *(short8*)dst = hv.s8;
    } else {
        short8 hi, lo;
        split8(fa, fb, hi, lo);
        *(short8*)dst = hi;
        *(short8*)(dst + 1024) = lo;
    }
}

// -------- main fused kernel: TWO batches per block, 8 waves, 3 blocks/CU --------
// LDS 53760 (S aliases TB, s4 held 4 regs across the drain barrier) -> 24
// waves/CU, +50% latency hiding vs R19's 2 blocks. Everything else identical
// to R19 (absmax must stay 0.00390625). Spill tripwire = WRITE_SIZE >> 76MB.
__global__ __launch_bounds__(512, 4)
void fused_net(const float* __restrict__ states, const uint8_t* __restrict__ wsb,
               float* __restrict__ out_policy, float* __restrict__ out_w1,
               float* __restrict__ out_w2) {
    __shared__ __align__(16) char smem[53760];

    const int b2   = blockIdx.x;       // batch pair index
    const int t    = threadIdx.x;
    const int w    = t >> 6;           // 0..7
    const int l    = t & 63;
    const int l31  = l & 31;
    const int half = l >> 5;
    const int l15  = l & 15;
    const int g4   = (l >> 4) & 3;
    const int rh   = w >> 2;           // row-half 0/1
    const int c4   = w & 3;            // col-tile 0..3

    // ---- stage 2 batches of X into the rne plane, coalesced ----
    {
        const float* src = states + (size_t)b2 * 8192;
#pragma unroll
        for (int r = 0; r < 4; ++r) {
            int flat = (t + 512 * r) * 4;
            int n = flat >> 7, d0 = flat & 127;    // n 0..63
            float4 v = *(const float4*)(src + flat);
            uint2 hw;
            hw.x = pack2_rne(v.x, v.y);
            hw.y = pack2_rne(v.z, v.w);
            *(uint2*)(smem + pl_addr(AH_OFF, n, d0)) = hw;
        }
    }
    __syncthreads();

#pragma unroll 1
    for (int blk = 0; blk < 2; ++blk) {
        const uint8_t* wb = wsb + (size_t)(blk * 2) * WSPROJ;   // [M, V] pair

        // ---- FUSED T/V projection ----
        {
            f32x16 tacc, vacc;
            gemm_tv(smem, wb, rh * 32, c4, l, tacc, vacc);
            store_plane32(smem, TB_OFF, rh * 32, c4, l, tacc);
            const int e = c4 * 32 + l31;
#pragma unroll
            for (int g = 0; g < 4; ++g) {                       // V merged b64 stores
                int m0 = rh * 32 + 8 * g + 4 * half;
                uint2 pk;
                pk.x = pack2_rne(vacc[4 * g],     vacc[4 * g + 1]);
                pk.y = pack2_rne(vacc[4 * g + 2], vacc[4 * g + 3]);
                *(uint2*)(smem + vt_addr(e, m0)) = pk;
            }
        }
        __builtin_amdgcn_sched_barrier(0);
        __syncthreads();                        // T/V visible; X reads done

        // ---- S = T X^T (scale folded): compute in regs, then overlay TB ----
        {
            const int bq = w >> 2, rb = (w >> 1) & 1, mb = w & 1;
            const int trow = bq * 32 + rb * 16 + l15;
            const int xrow = bq * 32 + mb * 16 + l15;
            f32x4 s4 = {0.f, 0.f, 0.f, 0.f};
#pragma unroll
            for (int kb = 0; kb < 4; ++kb) {
                int e0 = kb * 32 + g4 * 8;
                U4 th, xh;
                th.q = *(const uint4*)(smem + pl_addr(TB_OFF, trow, e0));
                xh.q = *(const uint4*)(smem + pl_addr(AH_OFF, xrow, e0));
                s4 = __builtin_amdgcn_mfma_f32_16x16x32_bf16(th.s8, xh.s8, s4, 0, 0, 0);
            }
            __syncthreads();                    // all T reads done (S aliases TB)
#pragma unroll
            for (int r = 0; r < 4; ++r) {
                int n = bq * 32 + rb * 16 + g4 * 4 + r;    // verified 16x16 D mapping
                *(float*)(smem + s_addr(n, mb * 16 + l15)) = s4[r];
            }
        }
        __syncthreads();

        // ---- softmax (ALL 512 threads): row n=t>>3, 4 cols each; 8-lane reduce;
        //      writes global weights (coalesced) + P rne plane ----
        {
            const int n  = t >> 3;
            const int mq = (t & 7) * 4;
            float4 v = *(const float4*)(smem + s_addr(n, mq));
            float mx = fmaxf(fmaxf(v.x, v.y), fmaxf(v.z, v.w));
            mx = fmaxf(mx, __shfl_xor(mx, 1));
            mx = fmaxf(mx, __shfl_xor(mx, 2));
            mx = fmaxf(mx, __shfl_xor(mx, 4));
            v.x = __expf(v.x - mx); v.y = __expf(v.y - mx);
            v.z = __expf(v.z - mx); v.w = __expf(v.w - mx);
            float s = v.x + v.y + v.z + v.w;
            s += __shfl_xor(s, 1);
            s += __shfl_xor(s, 2);
            s += __shfl_xor(s, 4);
            float inv = 1.0f / s;
            v.x *= inv; v.y *= inv; v.z *= inv; v.w *= inv;
            float* outw = blk ? out_w2 : out_w1;
            *(float4*)(outw + (size_t)b2 * 2048 + n * 32 + mq) = v;
            uint2 pb;
            pb.x = pack2_rne(v.x, v.y);
            pb.y = pack2_rne(v.z, v.w);
            *(uint2*)(smem + p_addr(n, mq)) = pb;
        }
        __syncthreads();

        // ---- PV: P (rne plane) x V (rne plane): 1 MFMA/kb; store -> ACT plane ----
        {
            const int bq = w >> 2;
            f32x16 pv = {0.f,0.f,0.f,0.f, 0.f,0.f,0.f,0.f, 0.f,0.f,0.f,0.f, 0.f,0.f,0.f,0.f};
            const int e = c4 * 32 + l31;
#pragma unroll
            for (int kb = 0; kb < 2; ++kb) {
                int m0 = kb * 16 + half * 8;
                U4 pa, vh;
                int pbase = p_addr(bq * 32 + l31, m0);
                *(uint2*)&pa.u[0] = *(const uint2*)(smem + pbase);
                *(uint2*)&pa.u[2] = *(const uint2*)(smem + pbase + 8);
                vh.q = *(const uint4*)(smem + vt_addr(e, bq * 32 + m0));
                pv = __builtin_amdgcn_mfma_f32_32x32x16_bf16(pa.s8, vh.s8, pv, 0, 0, 0);
            }
            store_plane32(smem, AH_OFF, bq * 32, c4, l, pv);   // WAV/NF rne
        }
        __builtin_amdgcn_sched_barrier(0);
        __syncthreads();
    }

    // ---- MLP hidden (fused 2 reps); H -> bf16 over dead TB+VT ----
    {
        f32x16 h0_, h1_;
        gemm_mlp2(smem, wsb + WP1OFF, rh * 32, c4, l, h0_, h1_);
#pragma unroll
        for (int rep = 0; rep < 2; ++rep) {
            const int hc = c4 + rep * 4;
            const int hcol = hc * 32 + l31;
#pragma unroll
            for (int r = 0; r < 16; ++r) {
                int n = rh * 32 + (r & 3) + 8 * (r >> 2) + 4 * half;
                float x = rep ? h1_[r] : h0_[r];
                x = fmaxf(x, 0.01f * x);            // leaky_relu
                *(uint16_t*)(smem + h_addr(n, hcol)) = f2bf_rne(x);
            }
        }
    }
    __syncthreads();

    // ---- policy logits: 4x 16x16 tiles (waves 0-3), K=256; logits -> dead AH ----
    if (w < 4) {
        f32x4 acc = {0.f, 0.f, 0.f, 0.f};
        const int n = w * 16 + l15;                 // rows 0..63
#pragma unroll
        for (int kb = 0; kb < 8; ++kb) {
            int h0 = kb * 32 + g4 * 8;
            U4 a;
            a.q = *(const uint4*)(smem + h_addr(n, h0));
            const uint8_t* p = wsb + WP2OFF + (size_t)(kb * 2) * 1024 + (size_t)l * 16;
            U4 bh, bl;
            bh.q = *(const uint4*)p;
            bl.q = *(const uint4*)(p + 1024);
            acc = __builtin_amdgcn_mfma_f32_16x16x32_bf16(a.s8, bh.s8, acc, 0, 0, 0);
            acc = __builtin_amdgcn_mfma_f32_16x16x32_bf16(a.s8, bl.s8, acc, 0, 0, 0);
        }
#pragma unroll
        for (int r = 0; r < 4; ++r) {
            int nn = w * 16 + g4 * 4 + r;
            *(float*)(smem + ps_addr(nn, l15)) = acc[r];
        }
    }
    __syncthreads();

    // ---- policy softmax over 10 actions (64 rows, wave 0) ----
    if (t < 64) {
        float v[10];
#pragma unroll
        for (int a2 = 0; a2 < 10; ++a2) v[a2] = *(const float*)(smem + ps_addr(t, a2));
        float mx = v[0];
#pragma unroll
        for (int a2 = 1; a2 < 10; ++a2) mx = fmaxf(mx, v[a2]);
        float sum = 0.f;
#pragma unroll
        for (int a2 = 0; a2 < 10; ++a2) { v[a2] = __expf(v[a2] - mx); sum += v[a2]; }
        float inv = 1.0f / sum;
#pragma unroll
        for (int a2 = 0; a2 < 10; ++a2) *(float*)(smem + ps_addr(t, a2)) = v[a2] * inv;
    }
    __syncthreads();

    for (int o = t; o < 640; o += 512) {
        int n = o / 10, a2 = o - n * 10;
        out_policy[(size_t)b2 * 640 + o] = *(const float*)(smem + ps_addr(n, a2));
    }
}

}  // namespace

extern "C" void kernel_launch(void* const* d_in, const int* in_sizes, int n_in,
                              void* d_out, int out_size, void* d_ws, size_t ws_size,
                              hipStream_t stream) {
    const float* states = (const float*)d_in[0];
    const float* Wk1 = (const float*)d_in[1];
    const float* Wq1 = (const float*)d_in[2];
    const float* Wv1 = (const float*)d_in[3];
    const float* Wk2 = (const float*)d_in[4];
    const float* Wq2 = (const float*)d_in[5];
    const float* Wv2 = (const float*)d_in[6];
    const float* Wp1 = (const float*)d_in[7];
    const float* Wp2 = (const float*)d_in[8];

    const int B = in_sizes[0] / 4096;   // 8192 batches

    uint8_t* wsb = (uint8_t*)d_ws;      // needs ~344 KB
    float* out        = (float*)d_out;
    float* out_policy = out;
    float* out_w1     = out_policy + (size_t)B * 320;
    float* out_w2     = out_w1 + (size_t)B * 1024;

    hipLaunchKernelGGL(prep_m, dim3(256), dim3(128), 0, stream,
                       Wq1, Wk1, Wq2, Wk2, wsb);
    hipLaunchKernelGGL(prepack, dim3(200), dim3(64), 0, stream,
                       Wv1, Wv2, Wp1, Wp2, wsb);
    hipLaunchKernelGGL(fused_net, dim3(B / 2), dim3(512), 0, stream,
                       states, wsb, out_policy, out_w1, out_w2);
}